// Round 3
// baseline (1345.720 us; speedup 1.0000x reference)
//
#include <hip/hip_runtime.h>
#include <math.h>

// Problem constants
#define TT   52        // time steps
#define BBAT 4         // batch
#define CCH  9         // input channels
#define HWP  4096      // 64*64 pixels per image
#define FF   64        // features
#define NP   16384     // b*h*w pixels
#define TD   5         // theta dim
#define NCC  6         // tessellation cells
#define TSTRIDE 147456 // b*c*h*w = 4*9*4096 (stride of t in x)

// output offsets (floats)
#define OUT0 0
#define OUT1 (NP*CCH*TT)        // 7667712  x_shift_pix
#define OUT2 (2*NP*CCH*TT)      // 15335424 theta_pred
#define OUT3 (OUT2 + NP*TD)     // 15417344 theta_shift

// workspace offsets (floats)
#define WS_BF    0     // 60 floats: CPAB basis
#define WS_WFOLD 256   // 64*16 floats: folded conv1 weights [f][16] = {b0, wA[0..8], pad}

// ---------------------------------------------------------------------------
// k_basis: reproduce np.linalg.svd(L) null-space basis (Vt[7:].T) exactly.
// (dgesdd LQ path; rows 8..12 of VT = e_{8..12}^T * H(7)...H(1).)
// ---------------------------------------------------------------------------
__global__ void k_basis(float* __restrict__ Bout) {
    int k = threadIdx.x;  // 64 lanes, cols 0..11 active
    double Acol[7], Vcol[7], Mcol[5];
#pragma unroll
    for (int r = 0; r < 7; r++) { Acol[r] = 0.0; Vcol[r] = 0.0; }
#pragma unroll
    for (int j = 0; j < 5; j++) Mcol[j] = 0.0;

    if (k < 12) {
#pragma unroll
        for (int j = 1; j < 6; j++) {
            int r = j - 1;
            double xj = (double)j / 6.0;
            if (k == 2 * (j - 1))     Acol[r] = xj;
            if (k == 2 * (j - 1) + 1) Acol[r] = 1.0;
            if (k == 2 * j)           Acol[r] = -xj;
            if (k == 2 * j + 1)       Acol[r] = -1.0;
        }
        if (k == 1)  Acol[5] = 1.0;
        if (k == 10) Acol[6] = 1.0;
        if (k == 11) Acol[6] = 1.0;
#pragma unroll
        for (int j = 0; j < 5; j++) Mcol[j] = (k == 7 + j) ? 1.0 : 0.0;
    }

    double tau[7];
#pragma unroll
    for (int i = 0; i < 7; i++) {
        double c = (k > i && k < 12) ? Acol[i] * Acol[i] : 0.0;
#pragma unroll
        for (int off = 1; off < 64; off <<= 1) c += __shfl_xor(c, off, 64);
        double alpha = __shfl(Acol[i], i, 64);
        double t_i, vk;
        if (c == 0.0) {
            t_i = 0.0;
            vk = (k == i) ? 1.0 : 0.0;
        } else {
            double nrm  = sqrt(alpha * alpha + c);
            double beta = (alpha >= 0.0) ? -nrm : nrm;  // Fortran SIGN convention
            t_i = (beta - alpha) / beta;
            double inv = 1.0 / (alpha - beta);
            vk = (k == i) ? 1.0 : ((k > i && k < 12) ? Acol[i] * inv : 0.0);
        }
        tau[i]  = t_i;
        Vcol[i] = vk;
#pragma unroll
        for (int r = 0; r < 7; r++) {
            if (r > i) {
                double w = Acol[r] * vk;
#pragma unroll
                for (int off = 1; off < 64; off <<= 1) w += __shfl_xor(w, off, 64);
                Acol[r] -= t_i * w * vk;
            }
        }
    }
#pragma unroll
    for (int i = 6; i >= 0; i--) {
#pragma unroll
        for (int j = 0; j < 5; j++) {
            double w = Mcol[j] * Vcol[i];
#pragma unroll
            for (int off = 1; off < 64; off <<= 1) w += __shfl_xor(w, off, 64);
            Mcol[j] -= tau[i] * w * Vcol[i];
        }
    }
    if (k < 12) {
#pragma unroll
        for (int j = 0; j < 5; j++) Bout[k * 5 + j] = (float)Mcol[j];
    }
}

// ---------------------------------------------------------------------------
// k_prep: fold LN_in into conv1 weights; wfold[f][16] = {b0, wA[0..8], pad}
//   y1[f] = relu(b0[f] + sum_c zc[c]*wA[c][f]),  zc = (x-m)*rsqrt(v+eps)
//   b0[f] = b1[f] + sum_c lnib[c]*w1[c][f];  wA[c][f] = lniw[c]*w1[c][f]
// ---------------------------------------------------------------------------
__global__ void k_prep(const float* __restrict__ lniw, const float* __restrict__ lnib,
                       const float* __restrict__ w1c,  const float* __restrict__ b1c,
                       float* __restrict__ wfold) {
    int f = threadIdx.x;
    if (f < 64) {
        float b0 = b1c[f];
#pragma unroll
        for (int c = 0; c < 9; ++c) {
            float wr = w1c[c * 64 + f];
            wfold[f * 16 + 1 + c] = lniw[c] * wr;
            b0 += lnib[c] * wr;
        }
        wfold[f * 16 + 0] = b0;
#pragma unroll
        for (int k = 10; k < 16; ++k) wfold[f * 16 + k] = 0.f;
    }
}

// ---------------------------------------------------------------------------
__global__ void k_theta_shift(const float* __restrict__ raw, float* __restrict__ out) {
    int i = blockIdx.x * blockDim.x + threadIdx.x;
    if (i < NP * TD) out[i] = 0.5f * raw[i];
}

// ---------------------------------------------------------------------------
// k_cpab: per (pixel n, grid point tt): theta@B^T -> per-cell (a,b),
// 100 Euler steps, lerp 9 channels.
// ---------------------------------------------------------------------------
__global__ __launch_bounds__(256) void k_cpab(
    const float* __restrict__ x,      // [52,4,9,64,64]
    const float* __restrict__ theta,  // [N,5]
    const float* __restrict__ Bf,     // [12,5]
    float scale,
    float* __restrict__ out)          // [N,9,52]
{
    int gid = blockIdx.x * blockDim.x + threadIdx.x;
    if (gid >= NP * TT) return;
    int n = gid / TT, tt = gid % TT;

    float th[TD];
#pragma unroll
    for (int j = 0; j < TD; j++) th[j] = scale * theta[n * TD + j];

    float a[NCC], b[NCC];
#pragma unroll
    for (int i = 0; i < NCC; i++) {
        float aa = 0.f, bb = 0.f;
#pragma unroll
        for (int j = 0; j < TD; j++) {
            aa += th[j] * Bf[(2 * i) * TD + j];
            bb += th[j] * Bf[(2 * i + 1) * TD + j];
        }
        a[i] = aa; b[i] = bb;
    }

    float xc = (float)tt / 51.0f;
    for (int s = 0; s < 100; ++s) {
        float t6 = xc * 6.0f;
        float av = t6 < 1.f ? a[0] : t6 < 2.f ? a[1] : t6 < 3.f ? a[2]
                 : t6 < 4.f ? a[3] : t6 < 5.f ? a[4] : a[5];
        float bv = t6 < 1.f ? b[0] : t6 < 2.f ? b[1] : t6 < 3.f ? b[2]
                 : t6 < 4.f ? b[3] : t6 < 5.f ? b[4] : b[5];
        xc = xc + 0.01f * (av * xc + bv);
        xc = fminf(fmaxf(xc, 0.0f), 1.0f);
    }

    float pos = xc * 51.0f;
    int x0 = (int)floorf(pos);
    if (x0 < 0) x0 = 0;
    if (x0 > 50) x0 = 50;
    float w = pos - (float)x0;
    int bb_ = n >> 12, p = n & 4095;
    int base0 = ((x0 * BBAT + bb_) * CCH) * HWP + p;
#pragma unroll
    for (int ch = 0; ch < CCH; ++ch) {
        float d0 = x[base0 + ch * HWP];
        float d1 = x[base0 + ch * HWP + TSTRIDE];
        out[n * (CCH * TT) + ch * TT + tt] = d0 * (1.0f - w) + d1 * w;
    }
}

// ---------------------------------------------------------------------------
// k_loc (transposed parallelization): wave = pixel, lane = time-position tt.
// All 64 features of a position live in the lane's registers (y2[64]).
//  - conv1/conv2/LN-affine weights are wave-uniform -> SGPR (s_load), zero DS
//  - LN64 is an in-lane reduction, zero shuffles
//  - fc1 rows read per-lane from L1/L2 (64B-stride float4, block-coherent)
// Lanes 52..63 idle: clamped loads, z masked to 0.
// ---------------------------------------------------------------------------
__global__ __launch_bounds__(256, 3) void k_loc(
    const float* __restrict__ x,     // [52,4,9,64,64]
    const float* __restrict__ xs,    // x_shift_pix [N,9,52]
    const float* __restrict__ wfold, // [64][16] folded conv1
    const float* __restrict__ w2c,   const float* __restrict__ b2c,
    const float* __restrict__ lncw,  const float* __restrict__ lncb,
    const float* __restrict__ fc1w,  const float* __restrict__ fc1b,
    const float* __restrict__ fc2w,  const float* __restrict__ fc2b,
    float* __restrict__ outtheta)    // [N,5]
{
    int lane = threadIdx.x & 63;
    int wv   = threadIdx.x >> 6;
    int n    = blockIdx.x * 4 + wv;
    int bb_  = n >> 12, p = n & 4095;
    int tt   = lane < 52 ? lane : 51;   // clamp for safe addressing
    bool valid = lane < TT;

    float acc[16];
#pragma unroll
    for (int j = 0; j < 16; ++j) acc[j] = 0.f;

    for (int beta = 0; beta < 2; ++beta) {
        // ---- load 9 channels for this lane's position ----
        float xin[9];
        if (beta == 0) {
            int base = ((tt * BBAT + bb_) * CCH) * HWP + p;
#pragma unroll
            for (int c = 0; c < 9; ++c) xin[c] = x[base + c * HWP];
        } else {
            int base = n * (CCH * TT) + tt;
#pragma unroll
            for (int c = 0; c < 9; ++c) xin[c] = xs[base + c * TT];
        }
        // ---- LN9 (in-lane) ----
        float s1 = 0.f, s2 = 0.f;
#pragma unroll
        for (int c = 0; c < 9; ++c) { s1 += xin[c]; s2 += xin[c] * xin[c]; }
        float m  = s1 * (1.0f / 9.0f);
        float v  = fmaxf(s2 * (1.0f / 9.0f) - m * m, 0.f);
        float rs = rsqrtf(v + 1e-5f);
        float zc[9];
#pragma unroll
        for (int c = 0; c < 9; ++c) zc[c] = (xin[c] - m) * rs;

        // ---- conv1 + conv2 fused: y2[g] = b2[g] + sum_f relu(y1_f) * W2[f][g]
        //      all weights wave-uniform (SGPR); y1_f never stored as array ----
        float y2[64];
#pragma unroll
        for (int g = 0; g < 64; ++g) y2[g] = b2c[g];
#pragma unroll 4
        for (int f = 0; f < 64; ++f) {
            const float* wf = wfold + f * 16;
            float y1 = wf[0];
#pragma unroll
            for (int c = 0; c < 9; ++c) y1 = fmaf(zc[c], wf[1 + c], y1);
            y1 = fmaxf(y1, 0.f);
            const float* w2row = w2c + f * 64;
#pragma unroll
            for (int g = 0; g < 64; ++g) y2[g] = fmaf(y1, w2row[g], y2[g]);
        }

        // ---- relu + LN64 moments (in-lane) ----
        float s = 0.f, q = 0.f;
#pragma unroll
        for (int g = 0; g < 64; ++g) {
            float t = fmaxf(y2[g], 0.f);
            y2[g] = t;
            s += t;
            q = fmaf(t, t, q);
        }
        float m2  = s * (1.0f / 64.0f);
        float v2  = fmaxf(q * (1.0f / 64.0f) - m2 * m2, 0.f);
        float rs2 = rsqrtf(v2 + 1e-5f);

        // ---- z2 + fc1 accumulation; fc1 row per (g, lane) from L1/L2 ----
        const float* frow = fc1w + ((size_t)(beta * 64) * TT + tt) * 16;
#pragma unroll 8
        for (int g = 0; g < 64; ++g) {
            float z = fmaf((y2[g] - m2) * rs2, lncw[g], lncb[g]);
            z = valid ? z : 0.f;
            const float4* r = (const float4*)(frow + (size_t)g * TT * 16);
            float4 r0 = r[0], r1 = r[1], r2 = r[2], r3 = r[3];
            acc[0]  = fmaf(z, r0.x, acc[0]);  acc[1]  = fmaf(z, r0.y, acc[1]);
            acc[2]  = fmaf(z, r0.z, acc[2]);  acc[3]  = fmaf(z, r0.w, acc[3]);
            acc[4]  = fmaf(z, r1.x, acc[4]);  acc[5]  = fmaf(z, r1.y, acc[5]);
            acc[6]  = fmaf(z, r1.z, acc[6]);  acc[7]  = fmaf(z, r1.w, acc[7]);
            acc[8]  = fmaf(z, r2.x, acc[8]);  acc[9]  = fmaf(z, r2.y, acc[9]);
            acc[10] = fmaf(z, r2.z, acc[10]); acc[11] = fmaf(z, r2.w, acc[11]);
            acc[12] = fmaf(z, r3.x, acc[12]); acc[13] = fmaf(z, r3.y, acc[13]);
            acc[14] = fmaf(z, r3.z, acc[14]); acc[15] = fmaf(z, r3.w, acc[15]);
        }
    }

    // ---- reduce acc over lanes (butterfly) ----
#pragma unroll
    for (int j = 0; j < 16; ++j) {
        float aj = acc[j];
#pragma unroll
        for (int off = 1; off < 64; off <<= 1) aj += __shfl_xor(aj, off, 64);
        acc[j] = aj;
    }
    // ---- fc2 + tanh ----
    if (lane < TD) {
        float o = fc2b[lane];
#pragma unroll
        for (int j = 0; j < 16; ++j) {
            float hj = fmaxf(acc[j] + fc1b[j], 0.f);
            o += hj * fc2w[j * TD + lane];
        }
        outtheta[n * TD + lane] = tanhf(o);
    }
}

// ---------------------------------------------------------------------------
extern "C" void kernel_launch(void* const* d_in, const int* in_sizes, int n_in,
                              void* d_out, int out_size, void* d_ws, size_t ws_size,
                              hipStream_t stream) {
    const float* x     = (const float*)d_in[0];
    const float* thraw = (const float*)d_in[1];
    const float* lniw  = (const float*)d_in[2];
    const float* lnib  = (const float*)d_in[3];
    const float* w1c   = (const float*)d_in[4];
    const float* b1c   = (const float*)d_in[5];
    const float* w2c   = (const float*)d_in[6];
    const float* b2c   = (const float*)d_in[7];
    const float* lncw  = (const float*)d_in[8];
    const float* lncb  = (const float*)d_in[9];
    const float* fc1w  = (const float*)d_in[10];
    const float* fc1b  = (const float*)d_in[11];
    const float* fc2w  = (const float*)d_in[12];
    const float* fc2b  = (const float*)d_in[13];
    float* out   = (float*)d_out;
    float* Bf    = (float*)d_ws + WS_BF;
    float* wfold = (float*)d_ws + WS_WFOLD;

    hipLaunchKernelGGL(k_basis, dim3(1), dim3(64), 0, stream, Bf);
    hipLaunchKernelGGL(k_prep, dim3(1), dim3(64), 0, stream, lniw, lnib, w1c, b1c, wfold);
    hipLaunchKernelGGL(k_theta_shift, dim3((NP * TD + 255) / 256), dim3(256), 0, stream,
                       thraw, out + OUT3);
    hipLaunchKernelGGL(k_cpab, dim3((NP * TT) / 256), dim3(256), 0, stream,
                       x, thraw, Bf, 0.5f, out + OUT1);
    hipLaunchKernelGGL(k_loc, dim3(NP / 4), dim3(256), 0, stream,
                       x, out + OUT1, wfold, w2c, b2c, lncw, lncb,
                       fc1w, fc1b, fc2w, fc2b, out + OUT2);
    hipLaunchKernelGGL(k_cpab, dim3((NP * TT) / 256), dim3(256), 0, stream,
                       x, out + OUT2, Bf, 1.0f, out + OUT0);
}

// Round 5
// 897.177 us; speedup vs baseline: 1.4999x; 1.4999x over previous
//
#include <hip/hip_runtime.h>
#include <math.h>

// Problem constants
#define TT   52        // time steps
#define BBAT 4         // batch
#define CCH  9         // input channels
#define HWP  4096      // 64*64 pixels per image
#define FF   64        // features
#define NP   16384     // b*h*w pixels
#define TD   5         // theta dim
#define NCC  6         // tessellation cells
#define TSTRIDE 147456 // b*c*h*w = 4*9*4096 (stride of t in x)

// output offsets (floats)
#define OUT0 0
#define OUT1 (NP*CCH*TT)        // 7667712  x_shift_pix
#define OUT2 (2*NP*CCH*TT)      // 15335424 theta_pred
#define OUT3 (OUT2 + NP*TD)     // 15417344 theta_shift

// ---------------------------------------------------------------------------
// DPP-based wave64 sum reduction (VALU pipe, zero DS ops).
// Sequence: quad xor1, quad xor2, row_half_mirror, row_mirror,
//           row_bcast15 (rows 1,3), row_bcast31 (rows 2,3) -> lane63 = total.
// ---------------------------------------------------------------------------
template <int CTRL, int RMASK>
__device__ __forceinline__ float dpp_mov(float v) {
    int r = __builtin_amdgcn_update_dpp(0, __builtin_bit_cast(int, v),
                                        CTRL, RMASK, 0xf, false);
    return __builtin_bit_cast(float, r);
}

__device__ __forceinline__ void wave_sum2_dpp(float& a, float& b) {
    a += dpp_mov<0xB1, 0xf>(a);  b += dpp_mov<0xB1, 0xf>(b);   // quad_perm [1,0,3,2]
    a += dpp_mov<0x4E, 0xf>(a);  b += dpp_mov<0x4E, 0xf>(b);   // quad_perm [2,3,0,1]
    a += dpp_mov<0x141, 0xf>(a); b += dpp_mov<0x141, 0xf>(b);  // row_half_mirror
    a += dpp_mov<0x140, 0xf>(a); b += dpp_mov<0x140, 0xf>(b);  // row_mirror
    a += dpp_mov<0x142, 0xa>(a); b += dpp_mov<0x142, 0xa>(b);  // row_bcast15
    a += dpp_mov<0x143, 0xc>(a); b += dpp_mov<0x143, 0xc>(b);  // row_bcast31
    a = __builtin_bit_cast(float, __builtin_amdgcn_readlane(__builtin_bit_cast(int, a), 63));
    b = __builtin_bit_cast(float, __builtin_amdgcn_readlane(__builtin_bit_cast(int, b), 63));
}

// ---------------------------------------------------------------------------
// k_basis: reproduce np.linalg.svd(L) null-space basis (Vt[7:].T) exactly.
// (dgesdd LQ path; rows 8..12 of VT = e_{8..12}^T * H(7)...H(1).)
// ---------------------------------------------------------------------------
__global__ void k_basis(float* __restrict__ Bout) {
    int k = threadIdx.x;  // 64 lanes, cols 0..11 active
    double Acol[7], Vcol[7], Mcol[5];
#pragma unroll
    for (int r = 0; r < 7; r++) { Acol[r] = 0.0; Vcol[r] = 0.0; }
#pragma unroll
    for (int j = 0; j < 5; j++) Mcol[j] = 0.0;

    if (k < 12) {
#pragma unroll
        for (int j = 1; j < 6; j++) {
            int r = j - 1;
            double xj = (double)j / 6.0;
            if (k == 2 * (j - 1))     Acol[r] = xj;
            if (k == 2 * (j - 1) + 1) Acol[r] = 1.0;
            if (k == 2 * j)           Acol[r] = -xj;
            if (k == 2 * j + 1)       Acol[r] = -1.0;
        }
        if (k == 1)  Acol[5] = 1.0;
        if (k == 10) Acol[6] = 1.0;
        if (k == 11) Acol[6] = 1.0;
#pragma unroll
        for (int j = 0; j < 5; j++) Mcol[j] = (k == 7 + j) ? 1.0 : 0.0;
    }

    double tau[7];
#pragma unroll
    for (int i = 0; i < 7; i++) {
        double c = (k > i && k < 12) ? Acol[i] * Acol[i] : 0.0;
#pragma unroll
        for (int off = 1; off < 64; off <<= 1) c += __shfl_xor(c, off, 64);
        double alpha = __shfl(Acol[i], i, 64);
        double t_i, vk;
        if (c == 0.0) {
            t_i = 0.0;
            vk = (k == i) ? 1.0 : 0.0;
        } else {
            double nrm  = sqrt(alpha * alpha + c);
            double beta = (alpha >= 0.0) ? -nrm : nrm;  // Fortran SIGN convention
            t_i = (beta - alpha) / beta;
            double inv = 1.0 / (alpha - beta);
            vk = (k == i) ? 1.0 : ((k > i && k < 12) ? Acol[i] * inv : 0.0);
        }
        tau[i]  = t_i;
        Vcol[i] = vk;
#pragma unroll
        for (int r = 0; r < 7; r++) {
            if (r > i) {
                double w = Acol[r] * vk;
#pragma unroll
                for (int off = 1; off < 64; off <<= 1) w += __shfl_xor(w, off, 64);
                Acol[r] -= t_i * w * vk;
            }
        }
    }
#pragma unroll
    for (int i = 6; i >= 0; i--) {
#pragma unroll
        for (int j = 0; j < 5; j++) {
            double w = Mcol[j] * Vcol[i];
#pragma unroll
            for (int off = 1; off < 64; off <<= 1) w += __shfl_xor(w, off, 64);
            Mcol[j] -= tau[i] * w * Vcol[i];
        }
    }
    if (k < 12) {
#pragma unroll
        for (int j = 0; j < 5; j++) Bout[k * 5 + j] = (float)Mcol[j];
    }
}

// ---------------------------------------------------------------------------
__global__ void k_theta_shift(const float* __restrict__ raw, float* __restrict__ out) {
    int i = blockIdx.x * blockDim.x + threadIdx.x;
    if (i < NP * TD) out[i] = 0.5f * raw[i];
}

// ---------------------------------------------------------------------------
// k_cpab: per (pixel n, grid point tt): theta@B^T -> per-cell (a,b),
// 100 Euler steps, lerp 9 channels.
// ---------------------------------------------------------------------------
__global__ __launch_bounds__(256) void k_cpab(
    const float* __restrict__ x,      // [52,4,9,64,64]
    const float* __restrict__ theta,  // [N,5]
    const float* __restrict__ Bf,     // [12,5]
    float scale,
    float* __restrict__ out)          // [N,9,52]
{
    int gid = blockIdx.x * blockDim.x + threadIdx.x;
    if (gid >= NP * TT) return;
    int n = gid / TT, tt = gid % TT;

    float th[TD];
#pragma unroll
    for (int j = 0; j < TD; j++) th[j] = scale * theta[n * TD + j];

    float a[NCC], b[NCC];
#pragma unroll
    for (int i = 0; i < NCC; i++) {
        float aa = 0.f, bb = 0.f;
#pragma unroll
        for (int j = 0; j < TD; j++) {
            aa += th[j] * Bf[(2 * i) * TD + j];
            bb += th[j] * Bf[(2 * i + 1) * TD + j];
        }
        a[i] = aa; b[i] = bb;
    }

    float xc = (float)tt / 51.0f;
    for (int s = 0; s < 100; ++s) {
        float t6 = xc * 6.0f;
        float av = t6 < 1.f ? a[0] : t6 < 2.f ? a[1] : t6 < 3.f ? a[2]
                 : t6 < 4.f ? a[3] : t6 < 5.f ? a[4] : a[5];
        float bv = t6 < 1.f ? b[0] : t6 < 2.f ? b[1] : t6 < 3.f ? b[2]
                 : t6 < 4.f ? b[3] : t6 < 5.f ? b[4] : b[5];
        xc = xc + 0.01f * (av * xc + bv);
        xc = fminf(fmaxf(xc, 0.0f), 1.0f);
    }

    float pos = xc * 51.0f;
    int x0 = (int)floorf(pos);
    if (x0 < 0) x0 = 0;
    if (x0 > 50) x0 = 50;
    float w = pos - (float)x0;
    int bb_ = n >> 12, p = n & 4095;
    int base0 = ((x0 * BBAT + bb_) * CCH) * HWP + p;
#pragma unroll
    for (int ch = 0; ch < CCH; ++ch) {
        float d0 = x[base0 + ch * HWP];
        float d1 = x[base0 + ch * HWP + TSTRIDE];
        out[n * (CCH * TT) + ch * TT + tt] = d0 * (1.0f - w) + d1 * w;
    }
}

// ---------------------------------------------------------------------------
// k_loc: fused localise(orig)+localise(shift)+fc1+fc2+tanh.
// 4 waves/block, wave wv = pixel blockIdx*4+wv, lane = feature f.
// DS-diet version of the round-2 pipeline (61 -> 22 DS ops/position):
//  - LN64 reduction via DPP (VALU) instead of 24 ds_bpermute shuffles
//  - fc1 weights in LDS as [f][16] float4s with 16B-unit XOR swizzle
//    (slot = (f*4+q) ^ (f&7), a bijection over 256 slots):
//    4 ds_read_b128 instead of 16 b32, 1 b128 store
//  - double-buffered, one barrier per position; next-position xin + fc1 row
//    prefetched to registers at iteration start
// NOTE: w1T MUST be [2][256] float4 (64 rows x 4 quarters per buffer) —
// round 4's [2][64] undersize was an OOB-LDS correctness bug.
// ---------------------------------------------------------------------------
__global__ __launch_bounds__(256, 3) void k_loc(
    const float* __restrict__ x,    // [52,4,9,64,64]
    const float* __restrict__ xs,   // x_shift_pix [N,9,52]
    const float* __restrict__ lniw, const float* __restrict__ lnib,
    const float* __restrict__ w1c,  const float* __restrict__ b1c,
    const float* __restrict__ w2c,  const float* __restrict__ b2c,
    const float* __restrict__ lncw, const float* __restrict__ lncb,
    const float* __restrict__ fc1w, const float* __restrict__ fc1b,
    const float* __restrict__ fc2w, const float* __restrict__ fc2b,
    float* __restrict__ outtheta)   // [N,5]
{
    __shared__ float y1L[4][64];          // per-wave y1 broadcast (no barrier)
    __shared__ float4 w1T[2][256];        // swizzled fc1 rows: [buf][(f*4+q)^(f&7)]

    int tid  = threadIdx.x;
    int lane = tid & 63;
    int wv   = tid >> 6;
    int n    = blockIdx.x * 4 + wv;
    int bb_  = n >> 12, p = n & 4095;

    // per-lane weights (resident for kernel lifetime)
    float w2col[64];
#pragma unroll
    for (int f = 0; f < 64; ++f) w2col[f] = w2c[f * 64 + lane];
    float wA[9];
    float bias0 = b1c[lane], sA = 0.f;
#pragma unroll
    for (int c = 0; c < 9; ++c) {
        float wr = w1c[c * 64 + lane];
        wA[c] = lniw[c] * wr;
        bias0 += lnib[c] * wr;
        sA += wA[c];
    }
    float b2r  = b2c[lane];
    float lnwr = lncw[lane], lnbr = lncb[lane];

    float acc[16];
#pragma unroll
    for (int j = 0; j < 16; ++j) acc[j] = 0.f;

    int swz_w = (lane * 4 + wv) ^ (lane & 7);   // staging slot for this thread

    // prologue: load pos 0 inputs, stage w1T[0]
    float xin[9];
    {
        int base = ((0 * BBAT + bb_) * CCH) * HWP + p;
#pragma unroll
        for (int c = 0; c < 9; ++c) xin[c] = x[base + c * HWP];
        int srow = lane * TT + 0;
        w1T[0][swz_w] = *(const float4*)(fc1w + srow * 16 + wv * 4);
    }
    __syncthreads();

    for (int pos = 0; pos < 2 * TT; ++pos) {
        int buf = pos & 1;
        int pn  = pos + 1;
        // ---- prefetch next position (regs) ----
        float xnx[9];
        float4 wnx;
        if (pn < 2 * TT) {
            int betan = (pn >= TT) ? 1 : 0;
            int ttn   = pn - betan * TT;
            if (!betan) {
                int base = ((ttn * BBAT + bb_) * CCH) * HWP + p;
#pragma unroll
                for (int c = 0; c < 9; ++c) xnx[c] = x[base + c * HWP];
            } else {
                int base = n * (CCH * TT) + ttn;
#pragma unroll
                for (int c = 0; c < 9; ++c) xnx[c] = xs[base + c * TT];
            }
            int srow = betan * (FF * TT) + lane * TT + ttn;
            wnx = *(const float4*)(fc1w + srow * 16 + wv * 4);
        }

        // ---- LN9 + conv1 (folded) ----
        float s1 = 0.f, s2 = 0.f, d9 = 0.f;
#pragma unroll
        for (int c = 0; c < 9; ++c) {
            s1 += xin[c];
            s2 += xin[c] * xin[c];
            d9 += xin[c] * wA[c];
        }
        float m = s1 * (1.0f / 9.0f);
        float v = fmaxf(s2 * (1.0f / 9.0f) - m * m, 0.f);
        float rs = rsqrtf(v + 1e-5f);
        float y1 = fmaxf(bias0 + rs * (d9 - m * sA), 0.f);
        y1L[wv][lane] = y1;

        // ---- conv2 (4 independent chains; y1 via b128 broadcast reads) ----
        float a0 = b2r, a1 = 0.f, a2 = 0.f, a3 = 0.f;
        const float4* y1v = (const float4*)y1L[wv];
#pragma unroll
        for (int k = 0; k < 16; ++k) {
            float4 yv = y1v[k];
            a0 += yv.x * w2col[4 * k + 0];
            a1 += yv.y * w2col[4 * k + 1];
            a2 += yv.z * w2col[4 * k + 2];
            a3 += yv.w * w2col[4 * k + 3];
        }
        float y2 = fmaxf((a0 + a1) + (a2 + a3), 0.f);

        // ---- LN64 (fused mean/var; DPP reduction, zero DS) ----
        float bs = y2, bq = y2 * y2;
        wave_sum2_dpp(bs, bq);
        float m2 = bs * (1.0f / 64.0f);
        float v2 = fmaxf(bq * (1.0f / 64.0f) - m2 * m2, 0.f);
        float z2 = (y2 - m2) * rsqrtf(v2 + 1e-5f) * lnwr + lnbr;

        // ---- fc1 partial accumulation: 4 swizzled b128 reads ----
#pragma unroll
        for (int q = 0; q < 4; ++q) {
            float4 r = w1T[buf][(lane * 4 + q) ^ (lane & 7)];
            acc[4 * q + 0] = fmaf(z2, r.x, acc[4 * q + 0]);
            acc[4 * q + 1] = fmaf(z2, r.y, acc[4 * q + 1]);
            acc[4 * q + 2] = fmaf(z2, r.z, acc[4 * q + 2]);
            acc[4 * q + 3] = fmaf(z2, r.w, acc[4 * q + 3]);
        }

        // ---- stage next buffer (one b128 store), advance pipeline ----
        if (pn < 2 * TT) {
            w1T[buf ^ 1][swz_w] = wnx;
#pragma unroll
            for (int c = 0; c < 9; ++c) xin[c] = xnx[c];
        }
        __syncthreads();
    }

    // reduce acc over lanes (butterfly -> all lanes hold totals)
#pragma unroll
    for (int j = 0; j < 16; ++j) {
        float aj = acc[j];
#pragma unroll
        for (int off = 1; off < 64; off <<= 1) aj += __shfl_xor(aj, off, 64);
        acc[j] = aj;
    }
    // fc2 + tanh
    if (lane < TD) {
        float o = fc2b[lane];
#pragma unroll
        for (int j = 0; j < 16; ++j) {
            float hj = fmaxf(acc[j] + fc1b[j], 0.f);
            o += hj * fc2w[j * TD + lane];
        }
        outtheta[n * TD + lane] = tanhf(o);
    }
}

// ---------------------------------------------------------------------------
extern "C" void kernel_launch(void* const* d_in, const int* in_sizes, int n_in,
                              void* d_out, int out_size, void* d_ws, size_t ws_size,
                              hipStream_t stream) {
    const float* x     = (const float*)d_in[0];
    const float* thraw = (const float*)d_in[1];
    const float* lniw  = (const float*)d_in[2];
    const float* lnib  = (const float*)d_in[3];
    const float* w1c   = (const float*)d_in[4];
    const float* b1c   = (const float*)d_in[5];
    const float* w2c   = (const float*)d_in[6];
    const float* b2c   = (const float*)d_in[7];
    const float* lncw  = (const float*)d_in[8];
    const float* lncb  = (const float*)d_in[9];
    const float* fc1w  = (const float*)d_in[10];
    const float* fc1b  = (const float*)d_in[11];
    const float* fc2w  = (const float*)d_in[12];
    const float* fc2b  = (const float*)d_in[13];
    float* out = (float*)d_out;
    float* Bf  = (float*)d_ws;  // 60 floats

    hipLaunchKernelGGL(k_basis, dim3(1), dim3(64), 0, stream, Bf);
    hipLaunchKernelGGL(k_theta_shift, dim3((NP * TD + 255) / 256), dim3(256), 0, stream,
                       thraw, out + OUT3);
    hipLaunchKernelGGL(k_cpab, dim3((NP * TT) / 256), dim3(256), 0, stream,
                       x, thraw, Bf, 0.5f, out + OUT1);
    hipLaunchKernelGGL(k_loc, dim3(NP / 4), dim3(256), 0, stream,
                       x, out + OUT1, lniw, lnib, w1c, b1c, w2c, b2c, lncw, lncb,
                       fc1w, fc1b, fc2w, fc2b, out + OUT2);
    hipLaunchKernelGGL(k_cpab, dim3((NP * TT) / 256), dim3(256), 0, stream,
                       x, out + OUT2, Bf, 1.0f, out + OUT0);
}

// Round 6
// 649.247 us; speedup vs baseline: 2.0727x; 1.3819x over previous
//
#include <hip/hip_runtime.h>
#include <math.h>

// Problem constants
#define TT   52        // time steps
#define BBAT 4         // batch
#define CCH  9         // input channels
#define HWP  4096      // 64*64 pixels per image
#define FF   64        // features
#define NP   16384     // b*h*w pixels
#define TD   5         // theta dim
#define NCC  6         // tessellation cells
#define TSTRIDE 147456 // b*c*h*w (stride of t in x, floats)

// output offsets (floats)
#define OUT0 0
#define OUT1 (NP*CCH*TT)        // x_shift_pix
#define OUT2 (2*NP*CCH*TT)      // theta_pred
#define OUT3 (OUT2 + NP*TD)     // theta_shift

typedef __attribute__((ext_vector_type(8)))  short short8v;
typedef __attribute__((ext_vector_type(4)))  float f32x4;
typedef __attribute__((ext_vector_type(4)))  int   int4v;
typedef __attribute__((ext_vector_type(2)))  int   int2v;

// RNE f32->bf16 bits, packed pair
__device__ __forceinline__ unsigned bfb(float f) {
    unsigned x = __builtin_bit_cast(unsigned, f);
    return (x + 0x7fffu + ((x >> 16) & 1u)) >> 16;
}
__device__ __forceinline__ unsigned pk2(float a, float b) {
    return bfb(a) | (bfb(b) << 16);
}

// ---------------------------------------------------------------------------
// k_basis: reproduce np.linalg.svd(L) null-space basis (Vt[7:].T) exactly.
// (dgesdd LQ path; rows 8..12 of VT = e_{8..12}^T * H(7)...H(1).)
// ---------------------------------------------------------------------------
__global__ void k_basis(float* __restrict__ Bout) {
    int k = threadIdx.x;
    double Acol[7], Vcol[7], Mcol[5];
#pragma unroll
    for (int r = 0; r < 7; r++) { Acol[r] = 0.0; Vcol[r] = 0.0; }
#pragma unroll
    for (int j = 0; j < 5; j++) Mcol[j] = 0.0;

    if (k < 12) {
#pragma unroll
        for (int j = 1; j < 6; j++) {
            int r = j - 1;
            double xj = (double)j / 6.0;
            if (k == 2 * (j - 1))     Acol[r] = xj;
            if (k == 2 * (j - 1) + 1) Acol[r] = 1.0;
            if (k == 2 * j)           Acol[r] = -xj;
            if (k == 2 * j + 1)       Acol[r] = -1.0;
        }
        if (k == 1)  Acol[5] = 1.0;
        if (k == 10) Acol[6] = 1.0;
        if (k == 11) Acol[6] = 1.0;
#pragma unroll
        for (int j = 0; j < 5; j++) Mcol[j] = (k == 7 + j) ? 1.0 : 0.0;
    }

    double tau[7];
#pragma unroll
    for (int i = 0; i < 7; i++) {
        double c = (k > i && k < 12) ? Acol[i] * Acol[i] : 0.0;
#pragma unroll
        for (int off = 1; off < 64; off <<= 1) c += __shfl_xor(c, off, 64);
        double alpha = __shfl(Acol[i], i, 64);
        double t_i, vk;
        if (c == 0.0) {
            t_i = 0.0;
            vk = (k == i) ? 1.0 : 0.0;
        } else {
            double nrm  = sqrt(alpha * alpha + c);
            double beta = (alpha >= 0.0) ? -nrm : nrm;  // Fortran SIGN
            t_i = (beta - alpha) / beta;
            double inv = 1.0 / (alpha - beta);
            vk = (k == i) ? 1.0 : ((k > i && k < 12) ? Acol[i] * inv : 0.0);
        }
        tau[i]  = t_i;
        Vcol[i] = vk;
#pragma unroll
        for (int r = 0; r < 7; r++) {
            if (r > i) {
                double w = Acol[r] * vk;
#pragma unroll
                for (int off = 1; off < 64; off <<= 1) w += __shfl_xor(w, off, 64);
                Acol[r] -= t_i * w * vk;
            }
        }
    }
#pragma unroll
    for (int i = 6; i >= 0; i--) {
#pragma unroll
        for (int j = 0; j < 5; j++) {
            double w = Mcol[j] * Vcol[i];
#pragma unroll
            for (int off = 1; off < 64; off <<= 1) w += __shfl_xor(w, off, 64);
            Mcol[j] -= tau[i] * w * Vcol[i];
        }
    }
    if (k < 12) {
#pragma unroll
        for (int j = 0; j < 5; j++) Bout[k * 5 + j] = (float)Mcol[j];
    }
}

// ---------------------------------------------------------------------------
__global__ void k_theta_shift(const float* __restrict__ raw, float* __restrict__ out) {
    int i = blockIdx.x * blockDim.x + threadIdx.x;
    if (i < NP * TD) out[i] = 0.5f * raw[i];
}

// ---------------------------------------------------------------------------
// k_cpab: unchanged (passing, ~30us each)
// ---------------------------------------------------------------------------
__global__ __launch_bounds__(256) void k_cpab(
    const float* __restrict__ x, const float* __restrict__ theta,
    const float* __restrict__ Bf, float scale, float* __restrict__ out)
{
    int gid = blockIdx.x * blockDim.x + threadIdx.x;
    if (gid >= NP * TT) return;
    int n = gid / TT, tt = gid % TT;

    float th[TD];
#pragma unroll
    for (int j = 0; j < TD; j++) th[j] = scale * theta[n * TD + j];

    float a[NCC], b[NCC];
#pragma unroll
    for (int i = 0; i < NCC; i++) {
        float aa = 0.f, bb = 0.f;
#pragma unroll
        for (int j = 0; j < TD; j++) {
            aa += th[j] * Bf[(2 * i) * TD + j];
            bb += th[j] * Bf[(2 * i + 1) * TD + j];
        }
        a[i] = aa; b[i] = bb;
    }

    float xc = (float)tt / 51.0f;
    for (int s = 0; s < 100; ++s) {
        float t6 = xc * 6.0f;
        float av = t6 < 1.f ? a[0] : t6 < 2.f ? a[1] : t6 < 3.f ? a[2]
                 : t6 < 4.f ? a[3] : t6 < 5.f ? a[4] : a[5];
        float bv = t6 < 1.f ? b[0] : t6 < 2.f ? b[1] : t6 < 3.f ? b[2]
                 : t6 < 4.f ? b[3] : t6 < 5.f ? b[4] : b[5];
        xc = xc + 0.01f * (av * xc + bv);
        xc = fminf(fmaxf(xc, 0.0f), 1.0f);
    }

    float pos = xc * 51.0f;
    int x0 = (int)floorf(pos);
    if (x0 < 0) x0 = 0;
    if (x0 > 50) x0 = 50;
    float w = pos - (float)x0;
    int bb_ = n >> 12, p = n & 4095;
    int base0 = ((x0 * BBAT + bb_) * CCH) * HWP + p;
#pragma unroll
    for (int ch = 0; ch < CCH; ++ch) {
        float d0 = x[base0 + ch * HWP];
        float d1 = x[base0 + ch * HWP + TSTRIDE];
        out[n * (CCH * TT) + ch * TT + tt] = d0 * (1.0f - w) + d1 * w;
    }
}

// ---------------------------------------------------------------------------
// k_loc (MFMA): wave = pixel; conv1/conv2 on matrix cores in bf16, everything
// else f32. Per wave:
//  Phase A: LN9 per lane (lane = position, 104 pos + pad to 112), zc->LDS
//           as B-fragment rows (lo: c0..7 | hi: c8, bias=1, 0...).
//  Tiles (7 x 16 positions):
//    conv1: C1[mt] = mfma_16x16x32_bf16(W1A[mt], zc-frag) ; relu -> y1buf
//           (LDS [pos][f] bf16, f XOR-swizzled by (pos&7)<<3)
//    conv2: C2[mt2] = b2 + sum_ks mfma(W2A[mt2][ks], y1-frag[ks]) ; relu
//    LN64:  lane holds 16 of 64 g for its pos; 2 shuffles (xor16/32)
//    fc1:   per lane 16 rows of fc1w (4x b128 each), acc[16] += z2*row
//  Epilogue: butterfly acc, fc2+tanh.
// W1 folds LN_in scale/bias via a bias channel: zc[9]=1, wAfold[9][f]=b0[f].
// ---------------------------------------------------------------------------
__global__ __launch_bounds__(256, 2) void k_loc(
    const float* __restrict__ x,    // [52,4,9,64,64]
    const float* __restrict__ xs,   // x_shift_pix [N,9,52]
    const float* __restrict__ lniw, const float* __restrict__ lnib,
    const float* __restrict__ w1c,  const float* __restrict__ b1c,
    const float* __restrict__ w2c,  const float* __restrict__ b2c,
    const float* __restrict__ lncw, const float* __restrict__ lncb,
    const float* __restrict__ fc1w, const float* __restrict__ fc1b,
    const float* __restrict__ fc2w, const float* __restrict__ fc2b,
    float* __restrict__ outtheta)   // [N,5]
{
    __shared__ unsigned short zcl[4][112][8];  // c0..7 per pos (bf16)
    __shared__ unsigned short zch[4][112][8];  // c8, bias, 0... per pos
    __shared__ unsigned short y1b[4][16][64];  // [pos][f^sw] bf16

    int tid  = threadIdx.x;
    int lane = tid & 63;
    int wv   = tid >> 6;
    int n    = blockIdx.x * 4 + wv;
    int bb_  = n >> 12, p = n & 4095;
    int pl   = lane & 15;     // position-in-tile / M-col
    int h    = lane >> 4;     // k-group

    // ---- build W1 A-fragments (M=f, K=c padded to 32; c9 = bias channel) ----
    short8v w1a[4];
#pragma unroll
    for (int mt = 0; mt < 4; ++mt) {
        int f = mt * 16 + pl;
        float b0f = b1c[f];
#pragma unroll
        for (int c = 0; c < 9; ++c) b0f += lnib[c] * w1c[c * 64 + f];
        float v[8];
#pragma unroll
        for (int i = 0; i < 8; ++i) {
            int c  = h * 8 + i;
            int cc = c < 9 ? c : 8;            // clamp (loads stay in-bounds)
            float lv = lniw[cc] * w1c[cc * 64 + f];
            v[i] = (c < 9) ? lv : ((c == 9) ? b0f : 0.f);
        }
        w1a[mt] = __builtin_bit_cast(short8v,
            (int4v){(int)pk2(v[0], v[1]), (int)pk2(v[2], v[3]),
                    (int)pk2(v[4], v[5]), (int)pk2(v[6], v[7])});
    }
    // ---- build W2 A-fragments (M=g, K=f=64 in 2 steps) ----
    short8v w2a[4][2];
#pragma unroll
    for (int mt2 = 0; mt2 < 4; ++mt2) {
        int g = mt2 * 16 + pl;
#pragma unroll
        for (int ks = 0; ks < 2; ++ks) {
            float v[8];
#pragma unroll
            for (int i = 0; i < 8; ++i) {
                int f = ks * 32 + h * 8 + i;
                v[i] = w2c[f * 64 + g];
            }
            w2a[mt2][ks] = __builtin_bit_cast(short8v,
                (int4v){(int)pk2(v[0], v[1]), (int)pk2(v[2], v[3]),
                        (int)pk2(v[4], v[5]), (int)pk2(v[6], v[7])});
        }
    }
    // ---- per-lane row constants: b2, lncw, lncb for g = mt2*16 + h*4 + r ----
    f32x4 b2v[4], lw4[4], lb4[4];
#pragma unroll
    for (int mt2 = 0; mt2 < 4; ++mt2) {
        b2v[mt2] = *(const f32x4*)(b2c  + mt2 * 16 + h * 4);
        lw4[mt2] = *(const f32x4*)(lncw + mt2 * 16 + h * 4);
        lb4[mt2] = *(const f32x4*)(lncb + mt2 * 16 + h * 4);
    }

    float acc[16];
#pragma unroll
    for (int j = 0; j < 16; ++j) acc[j] = 0.f;

    // ---- Phase A: LN9 per position, pack zc to LDS (pad 104..111 zeroed) ----
#pragma unroll
    for (int r = 0; r < 2; ++r) {
        int pos = r * 64 + lane;
        if (pos < 112) {
            float zc[9], bias;
            if (pos < 104) {
                int bt = pos >= 52 ? 1 : 0;
                int tt = pos - bt * 52;
                float xin[9];
                if (!bt) {
                    int base = ((tt * BBAT + bb_) * CCH) * HWP + p;
#pragma unroll
                    for (int c = 0; c < 9; ++c) xin[c] = x[base + c * HWP];
                } else {
                    int base = n * (CCH * TT) + tt;
#pragma unroll
                    for (int c = 0; c < 9; ++c) xin[c] = xs[base + c * TT];
                }
                float s1 = 0.f, s2 = 0.f;
#pragma unroll
                for (int c = 0; c < 9; ++c) { s1 += xin[c]; s2 += xin[c] * xin[c]; }
                float m  = s1 * (1.0f / 9.0f);
                float vv = fmaxf(s2 * (1.0f / 9.0f) - m * m, 0.f);
                float rs = rsqrtf(vv + 1e-5f);
#pragma unroll
                for (int c = 0; c < 9; ++c) zc[c] = (xin[c] - m) * rs;
                bias = 1.0f;
            } else {
#pragma unroll
                for (int c = 0; c < 9; ++c) zc[c] = 0.f;
                bias = 0.f;
            }
            *(int4v*)&zcl[wv][pos][0] =
                (int4v){(int)pk2(zc[0], zc[1]), (int)pk2(zc[2], zc[3]),
                        (int)pk2(zc[4], zc[5]), (int)pk2(zc[6], zc[7])};
            *(int4v*)&zch[wv][pos][0] = (int4v){(int)pk2(zc[8], bias), 0, 0, 0};
        }
    }

    // ---- tile loop ----
    for (int t = 0; t < 7; ++t) {
        int pos_g = t * 16 + pl;
        int sw    = (pos_g & 7) << 3;

        // conv1 B-fragment: lanes h==1 read hi row, else lo row (h>=2: A=0)
        const unsigned short* zrow = (h == 1) ? &zch[wv][pos_g][0] : &zcl[wv][pos_g][0];
        short8v b1f = *(const short8v*)zrow;

        // conv1 + relu -> y1buf (swizzled)
#pragma unroll
        for (int mt = 0; mt < 4; ++mt) {
            f32x4 c1 = __builtin_amdgcn_mfma_f32_16x16x32_bf16(
                w1a[mt], b1f, (f32x4){0.f, 0.f, 0.f, 0.f}, 0, 0, 0);
            float v0 = fmaxf(c1[0], 0.f), v1 = fmaxf(c1[1], 0.f);
            float v2 = fmaxf(c1[2], 0.f), v3 = fmaxf(c1[3], 0.f);
            int f0 = (mt * 16 + h * 4) ^ sw;
            *(int2v*)&y1b[wv][pl][f0] = (int2v){(int)pk2(v0, v1), (int)pk2(v2, v3)};
        }

        // conv2 B-fragments from y1buf
        short8v b2f0 = *(const short8v*)&y1b[wv][pl][(h * 8) ^ sw];
        short8v b2f1 = *(const short8v*)&y1b[wv][pl][(32 + h * 8) ^ sw];

        // conv2 + relu
        float y2[4][4];
#pragma unroll
        for (int mt2 = 0; mt2 < 4; ++mt2) {
            f32x4 c2 = b2v[mt2];
            c2 = __builtin_amdgcn_mfma_f32_16x16x32_bf16(w2a[mt2][0], b2f0, c2, 0, 0, 0);
            c2 = __builtin_amdgcn_mfma_f32_16x16x32_bf16(w2a[mt2][1], b2f1, c2, 0, 0, 0);
            y2[mt2][0] = fmaxf(c2[0], 0.f);
            y2[mt2][1] = fmaxf(c2[1], 0.f);
            y2[mt2][2] = fmaxf(c2[2], 0.f);
            y2[mt2][3] = fmaxf(c2[3], 0.f);
        }

        // LN64: lane has 16 of 64 g for its pos; finish with xor16/xor32
        float s = 0.f, q = 0.f;
#pragma unroll
        for (int mt2 = 0; mt2 < 4; ++mt2)
#pragma unroll
            for (int r = 0; r < 4; ++r) { s += y2[mt2][r]; q = fmaf(y2[mt2][r], y2[mt2][r], q); }
        s += __shfl_xor(s, 16, 64); s += __shfl_xor(s, 32, 64);
        q += __shfl_xor(q, 16, 64); q += __shfl_xor(q, 32, 64);
        float m2  = s * (1.0f / 64.0f);
        float v2_ = fmaxf(q * (1.0f / 64.0f) - m2 * m2, 0.f);
        float rs2 = rsqrtf(v2_ + 1e-5f);

        bool valid = pos_g < 104;
#pragma unroll
        for (int mt2 = 0; mt2 < 4; ++mt2)
#pragma unroll
            for (int r = 0; r < 4; ++r) {
                float z = fmaf((y2[mt2][r] - m2) * rs2, lw4[mt2][r], lb4[mt2][r]);
                y2[mt2][r] = valid ? z : 0.f;
            }

        // fc1: 16 rows per lane, 4x b128 each
        int bt  = pos_g >= 52 ? 1 : 0;
        int ttv = pos_g - bt * 52;
        if (ttv > 51) ttv = 51;  // pad lanes: clamp (z2 already 0)
        const float* fw = fc1w + (bt * 3328 + ttv) * 16;
#pragma unroll
        for (int mt2 = 0; mt2 < 4; ++mt2)
#pragma unroll
            for (int r = 0; r < 4; ++r) {
                int g = mt2 * 16 + h * 4 + r;
                const f32x4* rp = (const f32x4*)(fw + g * 832);
                f32x4 r0 = rp[0], r1 = rp[1], r2 = rp[2], r3 = rp[3];
                float z = y2[mt2][r];
                acc[0]  = fmaf(z, r0[0], acc[0]);  acc[1]  = fmaf(z, r0[1], acc[1]);
                acc[2]  = fmaf(z, r0[2], acc[2]);  acc[3]  = fmaf(z, r0[3], acc[3]);
                acc[4]  = fmaf(z, r1[0], acc[4]);  acc[5]  = fmaf(z, r1[1], acc[5]);
                acc[6]  = fmaf(z, r1[2], acc[6]);  acc[7]  = fmaf(z, r1[3], acc[7]);
                acc[8]  = fmaf(z, r2[0], acc[8]);  acc[9]  = fmaf(z, r2[1], acc[9]);
                acc[10] = fmaf(z, r2[2], acc[10]); acc[11] = fmaf(z, r2[3], acc[11]);
                acc[12] = fmaf(z, r3[0], acc[12]); acc[13] = fmaf(z, r3[1], acc[13]);
                acc[14] = fmaf(z, r3[2], acc[14]); acc[15] = fmaf(z, r3[3], acc[15]);
            }
        __syncthreads();   // keep the block's 4 waves in lockstep for L1 reuse
    }

    // ---- butterfly reduce acc over lanes ----
#pragma unroll
    for (int j = 0; j < 16; ++j) {
        float aj = acc[j];
#pragma unroll
        for (int off = 1; off < 64; off <<= 1) aj += __shfl_xor(aj, off, 64);
        acc[j] = aj;
    }
    // ---- fc2 + tanh ----
    if (lane < TD) {
        float o = fc2b[lane];
#pragma unroll
        for (int j = 0; j < 16; ++j) {
            float hj = fmaxf(acc[j] + fc1b[j], 0.f);
            o += hj * fc2w[j * TD + lane];
        }
        outtheta[n * TD + lane] = tanhf(o);
    }
}

// ---------------------------------------------------------------------------
extern "C" void kernel_launch(void* const* d_in, const int* in_sizes, int n_in,
                              void* d_out, int out_size, void* d_ws, size_t ws_size,
                              hipStream_t stream) {
    const float* x     = (const float*)d_in[0];
    const float* thraw = (const float*)d_in[1];
    const float* lniw  = (const float*)d_in[2];
    const float* lnib  = (const float*)d_in[3];
    const float* w1c   = (const float*)d_in[4];
    const float* b1c   = (const float*)d_in[5];
    const float* w2c   = (const float*)d_in[6];
    const float* b2c   = (const float*)d_in[7];
    const float* lncw  = (const float*)d_in[8];
    const float* lncb  = (const float*)d_in[9];
    const float* fc1w  = (const float*)d_in[10];
    const float* fc1b  = (const float*)d_in[11];
    const float* fc2w  = (const float*)d_in[12];
    const float* fc2b  = (const float*)d_in[13];
    float* out = (float*)d_out;
    float* Bf  = (float*)d_ws;  // 60 floats

    hipLaunchKernelGGL(k_basis, dim3(1), dim3(64), 0, stream, Bf);
    hipLaunchKernelGGL(k_theta_shift, dim3((NP * TD + 255) / 256), dim3(256), 0, stream,
                       thraw, out + OUT3);
    hipLaunchKernelGGL(k_cpab, dim3((NP * TT) / 256), dim3(256), 0, stream,
                       x, thraw, Bf, 0.5f, out + OUT1);
    hipLaunchKernelGGL(k_loc, dim3(NP / 4), dim3(256), 0, stream,
                       x, out + OUT1, lniw, lnib, w1c, b1c, w2c, b2c, lncw, lncb,
                       fc1w, fc1b, fc2w, fc2b, out + OUT2);
    hipLaunchKernelGGL(k_cpab, dim3((NP * TT) / 256), dim3(256), 0, stream,
                       x, out + OUT2, Bf, 1.0f, out + OUT0);
}

// Round 7
// 559.360 us; speedup vs baseline: 2.4058x; 1.1607x over previous
//
#include <hip/hip_runtime.h>
#include <math.h>

// Problem constants
#define TT   52        // time steps
#define BBAT 4         // batch
#define CCH  9         // input channels
#define HWP  4096      // 64*64 pixels per image
#define FF   64        // features
#define NP   16384     // b*h*w pixels
#define TD   5         // theta dim
#define NCC  6         // tessellation cells
#define TSTRIDE 147456 // b*c*h*w (stride of t in x, floats)

// output offsets (floats)
#define OUT0 0
#define OUT1 (NP*CCH*TT)        // x_shift_pix
#define OUT2 (2*NP*CCH*TT)      // theta_pred
#define OUT3 (OUT2 + NP*TD)     // theta_shift

typedef __attribute__((ext_vector_type(8)))  short short8v;
typedef __attribute__((ext_vector_type(4)))  float f32x4;
typedef __attribute__((ext_vector_type(4)))  int   int4v;
typedef __attribute__((ext_vector_type(2)))  int   int2v;

// RNE f32->bf16 bits, packed pair
__device__ __forceinline__ unsigned bfb(float f) {
    unsigned x = __builtin_bit_cast(unsigned, f);
    return (x + 0x7fffu + ((x >> 16) & 1u)) >> 16;
}
__device__ __forceinline__ unsigned pk2(float a, float b) {
    return bfb(a) | (bfb(b) << 16);
}

// ---------------------------------------------------------------------------
// k_basis: reproduce np.linalg.svd(L) null-space basis (Vt[7:].T) exactly.
// (dgesdd LQ path; rows 8..12 of VT = e_{8..12}^T * H(7)...H(1).)
// ---------------------------------------------------------------------------
__global__ void k_basis(float* __restrict__ Bout) {
    int k = threadIdx.x;
    double Acol[7], Vcol[7], Mcol[5];
#pragma unroll
    for (int r = 0; r < 7; r++) { Acol[r] = 0.0; Vcol[r] = 0.0; }
#pragma unroll
    for (int j = 0; j < 5; j++) Mcol[j] = 0.0;

    if (k < 12) {
#pragma unroll
        for (int j = 1; j < 6; j++) {
            int r = j - 1;
            double xj = (double)j / 6.0;
            if (k == 2 * (j - 1))     Acol[r] = xj;
            if (k == 2 * (j - 1) + 1) Acol[r] = 1.0;
            if (k == 2 * j)           Acol[r] = -xj;
            if (k == 2 * j + 1)       Acol[r] = -1.0;
        }
        if (k == 1)  Acol[5] = 1.0;
        if (k == 10) Acol[6] = 1.0;
        if (k == 11) Acol[6] = 1.0;
#pragma unroll
        for (int j = 0; j < 5; j++) Mcol[j] = (k == 7 + j) ? 1.0 : 0.0;
    }

    double tau[7];
#pragma unroll
    for (int i = 0; i < 7; i++) {
        double c = (k > i && k < 12) ? Acol[i] * Acol[i] : 0.0;
#pragma unroll
        for (int off = 1; off < 64; off <<= 1) c += __shfl_xor(c, off, 64);
        double alpha = __shfl(Acol[i], i, 64);
        double t_i, vk;
        if (c == 0.0) {
            t_i = 0.0;
            vk = (k == i) ? 1.0 : 0.0;
        } else {
            double nrm  = sqrt(alpha * alpha + c);
            double beta = (alpha >= 0.0) ? -nrm : nrm;  // Fortran SIGN
            t_i = (beta - alpha) / beta;
            double inv = 1.0 / (alpha - beta);
            vk = (k == i) ? 1.0 : ((k > i && k < 12) ? Acol[i] * inv : 0.0);
        }
        tau[i]  = t_i;
        Vcol[i] = vk;
#pragma unroll
        for (int r = 0; r < 7; r++) {
            if (r > i) {
                double w = Acol[r] * vk;
#pragma unroll
                for (int off = 1; off < 64; off <<= 1) w += __shfl_xor(w, off, 64);
                Acol[r] -= t_i * w * vk;
            }
        }
    }
#pragma unroll
    for (int i = 6; i >= 0; i--) {
#pragma unroll
        for (int j = 0; j < 5; j++) {
            double w = Mcol[j] * Vcol[i];
#pragma unroll
            for (int off = 1; off < 64; off <<= 1) w += __shfl_xor(w, off, 64);
            Mcol[j] -= tau[i] * w * Vcol[i];
        }
    }
    if (k < 12) {
#pragma unroll
        for (int j = 0; j < 5; j++) Bout[k * 5 + j] = (float)Mcol[j];
    }
}

// ---------------------------------------------------------------------------
__global__ void k_theta_shift(const float* __restrict__ raw, float* __restrict__ out) {
    int i = blockIdx.x * blockDim.x + threadIdx.x;
    if (i < NP * TD) out[i] = 0.5f * raw[i];
}

// ---------------------------------------------------------------------------
// k_cpab: unchanged (passing)
// ---------------------------------------------------------------------------
__global__ __launch_bounds__(256) void k_cpab(
    const float* __restrict__ x, const float* __restrict__ theta,
    const float* __restrict__ Bf, float scale, float* __restrict__ out)
{
    int gid = blockIdx.x * blockDim.x + threadIdx.x;
    if (gid >= NP * TT) return;
    int n = gid / TT, tt = gid % TT;

    float th[TD];
#pragma unroll
    for (int j = 0; j < TD; j++) th[j] = scale * theta[n * TD + j];

    float a[NCC], b[NCC];
#pragma unroll
    for (int i = 0; i < NCC; i++) {
        float aa = 0.f, bb = 0.f;
#pragma unroll
        for (int j = 0; j < TD; j++) {
            aa += th[j] * Bf[(2 * i) * TD + j];
            bb += th[j] * Bf[(2 * i + 1) * TD + j];
        }
        a[i] = aa; b[i] = bb;
    }

    float xc = (float)tt / 51.0f;
    for (int s = 0; s < 100; ++s) {
        float t6 = xc * 6.0f;
        float av = t6 < 1.f ? a[0] : t6 < 2.f ? a[1] : t6 < 3.f ? a[2]
                 : t6 < 4.f ? a[3] : t6 < 5.f ? a[4] : a[5];
        float bv = t6 < 1.f ? b[0] : t6 < 2.f ? b[1] : t6 < 3.f ? b[2]
                 : t6 < 4.f ? b[3] : t6 < 5.f ? b[4] : b[5];
        xc = xc + 0.01f * (av * xc + bv);
        xc = fminf(fmaxf(xc, 0.0f), 1.0f);
    }

    float pos = xc * 51.0f;
    int x0 = (int)floorf(pos);
    if (x0 < 0) x0 = 0;
    if (x0 > 50) x0 = 50;
    float w = pos - (float)x0;
    int bb_ = n >> 12, p = n & 4095;
    int base0 = ((x0 * BBAT + bb_) * CCH) * HWP + p;
#pragma unroll
    for (int ch = 0; ch < CCH; ++ch) {
        float d0 = x[base0 + ch * HWP];
        float d1 = x[base0 + ch * HWP + TSTRIDE];
        out[n * (CCH * TT) + ch * TT + tt] = d0 * (1.0f - w) + d1 * w;
    }
}

// ---------------------------------------------------------------------------
// k_loc (MFMA + LDS-staged fc1w): wave = pixel.
// Positions reordered into 8 bt-pure tiles of 16 (52 + 12 pad per branch),
// pos_g = t*16+pl -> bt = t>>2, tt = (pos_g&63), valid iff tt<52.
// Per tile:
//   stage: block cooperatively loads fc1w slice [VALID pos][64 g][16 j]
//          (contiguous 256 floats per g), converts bf16, stores to LDS in
//          XOR-swizzled 16B units: su = unit ^ ((pos&3)<<1) ^ ((g&12)>>1)
//          ^ ((pos>>2)&1)  (bijective; reads/writes spread over 8 bank-groups)
//   conv1/conv2 via mfma_16x16x32_bf16 (W fragments register-resident)
//   LN64 via xor16/xor32 shuffles
//   fc1: per lane 16 rows x 2 swizzled ds_read_b128 from staged tile
// ---------------------------------------------------------------------------
__global__ __launch_bounds__(256, 2) void k_loc(
    const float* __restrict__ x,    // [52,4,9,64,64]
    const float* __restrict__ xs,   // x_shift_pix [N,9,52]
    const float* __restrict__ lniw, const float* __restrict__ lnib,
    const float* __restrict__ w1c,  const float* __restrict__ b1c,
    const float* __restrict__ w2c,  const float* __restrict__ b2c,
    const float* __restrict__ lncw, const float* __restrict__ lncb,
    const float* __restrict__ fc1w, const float* __restrict__ fc1b,
    const float* __restrict__ fc2w, const float* __restrict__ fc2b,
    float* __restrict__ outtheta)   // [N,5]
{
    __shared__ unsigned short zcl[4][128][8];  // c0..7 per pos (bf16)
    __shared__ unsigned short zch[4][128][8];  // c8, bias, 0... per pos
    __shared__ unsigned short y1b[4][16][64];  // [pos][f^sw] bf16
    __shared__ int4v fcs[2048];                // 32KB staged fc1w tile (swizzled)

    int tid  = threadIdx.x;
    int lane = tid & 63;
    int wv   = tid >> 6;
    int n    = blockIdx.x * 4 + wv;
    int bb_  = n >> 12, p = n & 4095;
    int pl   = lane & 15;     // position-in-tile / N-col
    int h    = lane >> 4;     // k-group

    // ---- build W1 A-fragments (M=f, K=c padded to 32; c9 = bias channel) ----
    short8v w1a[4];
#pragma unroll
    for (int mt = 0; mt < 4; ++mt) {
        int f = mt * 16 + pl;
        float b0f = b1c[f];
#pragma unroll
        for (int c = 0; c < 9; ++c) b0f += lnib[c] * w1c[c * 64 + f];
        float v[8];
#pragma unroll
        for (int i = 0; i < 8; ++i) {
            int c  = h * 8 + i;
            int cc = c < 9 ? c : 8;
            float lv = lniw[cc] * w1c[cc * 64 + f];
            v[i] = (c < 9) ? lv : ((c == 9) ? b0f : 0.f);
        }
        w1a[mt] = __builtin_bit_cast(short8v,
            (int4v){(int)pk2(v[0], v[1]), (int)pk2(v[2], v[3]),
                    (int)pk2(v[4], v[5]), (int)pk2(v[6], v[7])});
    }
    // ---- build W2 A-fragments (M=g, K=f=64 in 2 steps) ----
    short8v w2a[4][2];
#pragma unroll
    for (int mt2 = 0; mt2 < 4; ++mt2) {
        int g = mt2 * 16 + pl;
#pragma unroll
        for (int ks = 0; ks < 2; ++ks) {
            float v[8];
#pragma unroll
            for (int i = 0; i < 8; ++i) {
                int f = ks * 32 + h * 8 + i;
                v[i] = w2c[f * 64 + g];
            }
            w2a[mt2][ks] = __builtin_bit_cast(short8v,
                (int4v){(int)pk2(v[0], v[1]), (int)pk2(v[2], v[3]),
                        (int)pk2(v[4], v[5]), (int)pk2(v[6], v[7])});
        }
    }
    // ---- per-lane row constants for g = mt2*16 + h*4 + r ----
    f32x4 b2v[4], lw4[4], lb4[4];
#pragma unroll
    for (int mt2 = 0; mt2 < 4; ++mt2) {
        b2v[mt2] = *(const f32x4*)(b2c  + mt2 * 16 + h * 4);
        lw4[mt2] = *(const f32x4*)(lncw + mt2 * 16 + h * 4);
        lb4[mt2] = *(const f32x4*)(lncb + mt2 * 16 + h * 4);
    }

    float acc[16];
#pragma unroll
    for (int j = 0; j < 16; ++j) acc[j] = 0.f;

    // ---- Phase A: LN9 per position (128 slots: 2 branches x 64, tt<52 valid) ----
#pragma unroll
    for (int r = 0; r < 2; ++r) {
        int pos = r * 64 + lane;
        int bt  = pos >> 6;
        int tt  = pos & 63;
        float zc[9], bias;
        if (tt < 52) {
            float xin[9];
            if (!bt) {
                int base = ((tt * BBAT + bb_) * CCH) * HWP + p;
#pragma unroll
                for (int c = 0; c < 9; ++c) xin[c] = x[base + c * HWP];
            } else {
                int base = n * (CCH * TT) + tt;
#pragma unroll
                for (int c = 0; c < 9; ++c) xin[c] = xs[base + c * TT];
            }
            float s1 = 0.f, s2 = 0.f;
#pragma unroll
            for (int c = 0; c < 9; ++c) { s1 += xin[c]; s2 += xin[c] * xin[c]; }
            float m  = s1 * (1.0f / 9.0f);
            float vv = fmaxf(s2 * (1.0f / 9.0f) - m * m, 0.f);
            float rs = rsqrtf(vv + 1e-5f);
#pragma unroll
            for (int c = 0; c < 9; ++c) zc[c] = (xin[c] - m) * rs;
            bias = 1.0f;
        } else {
#pragma unroll
            for (int c = 0; c < 9; ++c) zc[c] = 0.f;
            bias = 0.f;
        }
        *(int4v*)&zcl[wv][pos][0] =
            (int4v){(int)pk2(zc[0], zc[1]), (int)pk2(zc[2], zc[3]),
                    (int)pk2(zc[4], zc[5]), (int)pk2(zc[6], zc[7])};
        *(int4v*)&zch[wv][pos][0] = (int4v){(int)pk2(zc[8], bias), 0, 0, 0};
    }

    // ---- tile loop (8 bt-pure tiles of 16 positions) ----
    for (int t = 0; t < 8; ++t) {
        // ---- stage fc1w slice to LDS (coalesced, bf16, swizzled) ----
        {
            int bt  = t >> 2;
            int tt0 = (t & 3) << 4;
            int VAL = ((t & 3) == 3) ? 4 : 16;   // valid positions in tile
            int total = VAL * 128;               // 16B units
            const float* srcb = fc1w + (bt * 3328 + tt0) * 16;
            for (int u = tid; u < total; u += 256) {
                int g, rem;
                if (VAL == 16) { g = u >> 5; rem = u & 31; }
                else           { g = u >> 3; rem = u & 7;  }
                int pos_l = rem >> 1, q = rem & 1;
                const float* s = srcb + (g * 52 + pos_l) * 16 + q * 8;
                float4 f0 = *(const float4*)s;
                float4 f1 = *(const float4*)(s + 4);
                int unit = (((pos_l << 6) + g) << 1) + q;
                int m = (((pos_l & 3) << 1) ^ ((g & 12) >> 1)) | ((pos_l >> 2) & 1);
                fcs[unit ^ m] = (int4v){(int)pk2(f0.x, f0.y), (int)pk2(f0.z, f0.w),
                                        (int)pk2(f1.x, f1.y), (int)pk2(f1.z, f1.w)};
            }
        }
        __syncthreads();

        int pos_g = t * 16 + pl;
        int sw    = (pl & 7) << 3;

        // conv1 B-fragment (h==1 reads hi row; h>=2: A=0 so garbage ok)
        const unsigned short* zrow = (h == 1) ? &zch[wv][pos_g][0] : &zcl[wv][pos_g][0];
        short8v b1f = *(const short8v*)zrow;

        // conv1 + relu -> y1buf (swizzled)
#pragma unroll
        for (int mt = 0; mt < 4; ++mt) {
            f32x4 c1 = __builtin_amdgcn_mfma_f32_16x16x32_bf16(
                w1a[mt], b1f, (f32x4){0.f, 0.f, 0.f, 0.f}, 0, 0, 0);
            float v0 = fmaxf(c1[0], 0.f), v1 = fmaxf(c1[1], 0.f);
            float v2 = fmaxf(c1[2], 0.f), v3 = fmaxf(c1[3], 0.f);
            int f0 = (mt * 16 + h * 4) ^ sw;
            *(int2v*)&y1b[wv][pl][f0] = (int2v){(int)pk2(v0, v1), (int)pk2(v2, v3)};
        }

        // conv2 B-fragments from y1buf
        short8v b2f0 = *(const short8v*)&y1b[wv][pl][(h * 8) ^ sw];
        short8v b2f1 = *(const short8v*)&y1b[wv][pl][(32 + h * 8) ^ sw];

        // conv2 + relu
        float y2[4][4];
#pragma unroll
        for (int mt2 = 0; mt2 < 4; ++mt2) {
            f32x4 c2 = b2v[mt2];
            c2 = __builtin_amdgcn_mfma_f32_16x16x32_bf16(w2a[mt2][0], b2f0, c2, 0, 0, 0);
            c2 = __builtin_amdgcn_mfma_f32_16x16x32_bf16(w2a[mt2][1], b2f1, c2, 0, 0, 0);
            y2[mt2][0] = fmaxf(c2[0], 0.f);
            y2[mt2][1] = fmaxf(c2[1], 0.f);
            y2[mt2][2] = fmaxf(c2[2], 0.f);
            y2[mt2][3] = fmaxf(c2[3], 0.f);
        }

        // LN64 per position: in-lane 16 + xor16/xor32
        float s = 0.f, q = 0.f;
#pragma unroll
        for (int mt2 = 0; mt2 < 4; ++mt2)
#pragma unroll
            for (int r = 0; r < 4; ++r) { s += y2[mt2][r]; q = fmaf(y2[mt2][r], y2[mt2][r], q); }
        s += __shfl_xor(s, 16, 64); s += __shfl_xor(s, 32, 64);
        q += __shfl_xor(q, 16, 64); q += __shfl_xor(q, 32, 64);
        float m2  = s * (1.0f / 64.0f);
        float v2_ = fmaxf(q * (1.0f / 64.0f) - m2 * m2, 0.f);
        float rs2 = rsqrtf(v2_ + 1e-5f);

        bool valid = (pos_g & 63) < 52;
#pragma unroll
        for (int mt2 = 0; mt2 < 4; ++mt2)
#pragma unroll
            for (int r = 0; r < 4; ++r) {
                float z = fmaf((y2[mt2][r] - m2) * rs2, lw4[mt2][r], lb4[mt2][r]);
                y2[mt2][r] = valid ? z : 0.f;
            }

        // fc1: 16 rows per lane from staged LDS (2 swizzled b128 per row)
#pragma unroll
        for (int mt2 = 0; mt2 < 4; ++mt2)
#pragma unroll
            for (int r = 0; r < 4; ++r) {
                int g = mt2 * 16 + h * 4 + r;
                float z = y2[mt2][r];
                int m  = (((pl & 3) << 1) ^ ((g & 12) >> 1)) | ((pl >> 2) & 1);
                int su0 = ((((pl << 6) + g) << 1)) ^ m;
                int4v a0 = fcs[su0];
                int4v a1 = fcs[su0 ^ 1];
#pragma unroll
                for (int w = 0; w < 4; ++w) {
                    unsigned u0 = (unsigned)a0[w];
                    acc[2*w+0] = fmaf(z, __builtin_bit_cast(float, u0 << 16), acc[2*w+0]);
                    acc[2*w+1] = fmaf(z, __builtin_bit_cast(float, u0 & 0xffff0000u), acc[2*w+1]);
                    unsigned u1 = (unsigned)a1[w];
                    acc[8+2*w+0] = fmaf(z, __builtin_bit_cast(float, u1 << 16), acc[8+2*w+0]);
                    acc[8+2*w+1] = fmaf(z, __builtin_bit_cast(float, u1 & 0xffff0000u), acc[8+2*w+1]);
                }
            }
        __syncthreads();   // all reads done before next tile's staging overwrite
    }

    // ---- butterfly reduce acc over lanes ----
#pragma unroll
    for (int j = 0; j < 16; ++j) {
        float aj = acc[j];
#pragma unroll
        for (int off = 1; off < 64; off <<= 1) aj += __shfl_xor(aj, off, 64);
        acc[j] = aj;
    }
    // ---- fc2 + tanh ----
    if (lane < TD) {
        float o = fc2b[lane];
#pragma unroll
        for (int j = 0; j < 16; ++j) {
            float hj = fmaxf(acc[j] + fc1b[j], 0.f);
            o += hj * fc2w[j * TD + lane];
        }
        outtheta[n * TD + lane] = tanhf(o);
    }
}

// ---------------------------------------------------------------------------
extern "C" void kernel_launch(void* const* d_in, const int* in_sizes, int n_in,
                              void* d_out, int out_size, void* d_ws, size_t ws_size,
                              hipStream_t stream) {
    const float* x     = (const float*)d_in[0];
    const float* thraw = (const float*)d_in[1];
    const float* lniw  = (const float*)d_in[2];
    const float* lnib  = (const float*)d_in[3];
    const float* w1c   = (const float*)d_in[4];
    const float* b1c   = (const float*)d_in[5];
    const float* w2c   = (const float*)d_in[6];
    const float* b2c   = (const float*)d_in[7];
    const float* lncw  = (const float*)d_in[8];
    const float* lncb  = (const float*)d_in[9];
    const float* fc1w  = (const float*)d_in[10];
    const float* fc1b  = (const float*)d_in[11];
    const float* fc2w  = (const float*)d_in[12];
    const float* fc2b  = (const float*)d_in[13];
    float* out = (float*)d_out;
    float* Bf  = (float*)d_ws;  // 60 floats

    hipLaunchKernelGGL(k_basis, dim3(1), dim3(64), 0, stream, Bf);
    hipLaunchKernelGGL(k_theta_shift, dim3((NP * TD + 255) / 256), dim3(256), 0, stream,
                       thraw, out + OUT3);
    hipLaunchKernelGGL(k_cpab, dim3((NP * TT) / 256), dim3(256), 0, stream,
                       x, thraw, Bf, 0.5f, out + OUT1);
    hipLaunchKernelGGL(k_loc, dim3(NP / 4), dim3(256), 0, stream,
                       x, out + OUT1, lniw, lnib, w1c, b1c, w2c, b2c, lncw, lncb,
                       fc1w, fc1b, fc2w, fc2b, out + OUT2);
    hipLaunchKernelGGL(k_cpab, dim3((NP * TT) / 256), dim3(256), 0, stream,
                       x, out + OUT2, Bf, 1.0f, out + OUT0);
}

// Round 8
// 445.213 us; speedup vs baseline: 3.0226x; 1.2564x over previous
//
#include <hip/hip_runtime.h>
#include <math.h>

// Problem constants
#define TT   52        // time steps
#define BBAT 4         // batch
#define CCH  9         // input channels
#define HWP  4096      // 64*64 pixels per image
#define FF   64        // features
#define NP   16384     // b*h*w pixels
#define TD   5         // theta dim
#define NCC  6         // tessellation cells
#define TSTRIDE 147456 // b*c*h*w (stride of t in x, floats)

// output offsets (floats)
#define OUT0 0
#define OUT1 (NP*CCH*TT)        // x_shift_pix
#define OUT2 (2*NP*CCH*TT)      // theta_pred
#define OUT3 (OUT2 + NP*TD)     // theta_shift

// workspace offsets (floats). total usage ~272KB.
#define WS_BF    0      // 60 floats: CPAB basis
#define WS_WIMG  1024   // 12*64 int4 = 3072 floats: w1a/w2a fragment image
#define WS_AIMG  4096   // 8*32*64 int4 = 65536 floats: fc1w A-fragment image

typedef __attribute__((ext_vector_type(8)))  short short8v;
typedef __attribute__((ext_vector_type(4)))  float f32x4;
typedef __attribute__((ext_vector_type(4)))  int   int4v;
typedef __attribute__((ext_vector_type(2)))  int   int2v;

// RNE f32->bf16 bits, packed pair
__device__ __forceinline__ unsigned bfb(float f) {
    unsigned x = __builtin_bit_cast(unsigned, f);
    return (x + 0x7fffu + ((x >> 16) & 1u)) >> 16;
}
__device__ __forceinline__ unsigned pk2(float a, float b) {
    return bfb(a) | (bfb(b) << 16);
}

// ---------------------------------------------------------------------------
// k_basis: reproduce np.linalg.svd(L) null-space basis (Vt[7:].T) exactly.
// ---------------------------------------------------------------------------
__global__ void k_basis(float* __restrict__ Bout) {
    int k = threadIdx.x;
    double Acol[7], Vcol[7], Mcol[5];
#pragma unroll
    for (int r = 0; r < 7; r++) { Acol[r] = 0.0; Vcol[r] = 0.0; }
#pragma unroll
    for (int j = 0; j < 5; j++) Mcol[j] = 0.0;

    if (k < 12) {
#pragma unroll
        for (int j = 1; j < 6; j++) {
            int r = j - 1;
            double xj = (double)j / 6.0;
            if (k == 2 * (j - 1))     Acol[r] = xj;
            if (k == 2 * (j - 1) + 1) Acol[r] = 1.0;
            if (k == 2 * j)           Acol[r] = -xj;
            if (k == 2 * j + 1)       Acol[r] = -1.0;
        }
        if (k == 1)  Acol[5] = 1.0;
        if (k == 10) Acol[6] = 1.0;
        if (k == 11) Acol[6] = 1.0;
#pragma unroll
        for (int j = 0; j < 5; j++) Mcol[j] = (k == 7 + j) ? 1.0 : 0.0;
    }

    double tau[7];
#pragma unroll
    for (int i = 0; i < 7; i++) {
        double c = (k > i && k < 12) ? Acol[i] * Acol[i] : 0.0;
#pragma unroll
        for (int off = 1; off < 64; off <<= 1) c += __shfl_xor(c, off, 64);
        double alpha = __shfl(Acol[i], i, 64);
        double t_i, vk;
        if (c == 0.0) {
            t_i = 0.0;
            vk = (k == i) ? 1.0 : 0.0;
        } else {
            double nrm  = sqrt(alpha * alpha + c);
            double beta = (alpha >= 0.0) ? -nrm : nrm;  // Fortran SIGN
            t_i = (beta - alpha) / beta;
            double inv = 1.0 / (alpha - beta);
            vk = (k == i) ? 1.0 : ((k > i && k < 12) ? Acol[i] * inv : 0.0);
        }
        tau[i]  = t_i;
        Vcol[i] = vk;
#pragma unroll
        for (int r = 0; r < 7; r++) {
            if (r > i) {
                double w = Acol[r] * vk;
#pragma unroll
                for (int off = 1; off < 64; off <<= 1) w += __shfl_xor(w, off, 64);
                Acol[r] -= t_i * w * vk;
            }
        }
    }
#pragma unroll
    for (int i = 6; i >= 0; i--) {
#pragma unroll
        for (int j = 0; j < 5; j++) {
            double w = Mcol[j] * Vcol[i];
#pragma unroll
            for (int off = 1; off < 64; off <<= 1) w += __shfl_xor(w, off, 64);
            Mcol[j] -= tau[i] * w * Vcol[i];
        }
    }
    if (k < 12) {
#pragma unroll
        for (int j = 0; j < 5; j++) Bout[k * 5 + j] = (float)Mcol[j];
    }
}

// ---------------------------------------------------------------------------
// k_prepw: build conv1/conv2 MFMA A-fragments once -> wimg[12][64] int4.
// unit u<4: w1a[mt=u]; u=4+mt2*2+ks: w2a[mt2][ks].
// ---------------------------------------------------------------------------
__global__ void k_prepw(const float* __restrict__ lniw, const float* __restrict__ lnib,
                        const float* __restrict__ w1c,  const float* __restrict__ b1c,
                        const float* __restrict__ w2c,  int4v* __restrict__ wimg) {
    int lane = threadIdx.x;
    int pl = lane & 15, h = lane >> 4;
#pragma unroll
    for (int mt = 0; mt < 4; ++mt) {
        int f = mt * 16 + pl;
        float b0f = b1c[f];
#pragma unroll
        for (int c = 0; c < 9; ++c) b0f += lnib[c] * w1c[c * 64 + f];
        float v[8];
#pragma unroll
        for (int i = 0; i < 8; ++i) {
            int c  = h * 8 + i;
            int cc = c < 9 ? c : 8;
            float lv = lniw[cc] * w1c[cc * 64 + f];
            v[i] = (c < 9) ? lv : ((c == 9) ? b0f : 0.f);
        }
        wimg[mt * 64 + lane] = (int4v){(int)pk2(v[0],v[1]), (int)pk2(v[2],v[3]),
                                       (int)pk2(v[4],v[5]), (int)pk2(v[6],v[7])};
    }
#pragma unroll
    for (int mt2 = 0; mt2 < 4; ++mt2) {
        int g = mt2 * 16 + pl;
#pragma unroll
        for (int ks = 0; ks < 2; ++ks) {
            float v[8];
#pragma unroll
            for (int i = 0; i < 8; ++i) v[i] = w2c[(ks * 32 + h * 8 + i) * 64 + g];
            wimg[(4 + mt2 * 2 + ks) * 64 + lane] =
                (int4v){(int)pk2(v[0],v[1]), (int)pk2(v[2],v[3]),
                        (int)pk2(v[4],v[5]), (int)pk2(v[6],v[7])};
        }
    }
}

// ---------------------------------------------------------------------------
// k_prepa: fc1w -> bf16 A-fragment image. aimg[(t*32+c)*64+lane] holds
// A[m = lane&15][k = c*32 + (lane>>4)*8 + i], k enumerates (pos_l*64 + g)
// within tile t (bt = t>>2, tt = (t&3)*16 + pos_l). Pad positions = 0.
// ---------------------------------------------------------------------------
__global__ void k_prepa(const float* __restrict__ fc1w, int4v* __restrict__ aimg) {
    int gid  = blockIdx.x * 256 + threadIdx.x;   // 16384 total
    int lane = gid & 63;
    int tc   = gid >> 6;
    int t = tc >> 5, c = tc & 31;
    int bt = t >> 2, tt0 = (t & 3) << 4;
    int m = lane & 15, h = lane >> 4;
    float v[8];
#pragma unroll
    for (int i = 0; i < 8; ++i) {
        int k = c * 32 + h * 8 + i;
        int pos_l = k >> 6, g = k & 63;
        int tt = tt0 + pos_l;
        v[i] = (tt < 52) ? fc1w[(bt * 3328 + g * 52 + tt) * 16 + m] : 0.f;
    }
    aimg[gid] = (int4v){(int)pk2(v[0],v[1]), (int)pk2(v[2],v[3]),
                        (int)pk2(v[4],v[5]), (int)pk2(v[6],v[7])};
}

// ---------------------------------------------------------------------------
__global__ void k_theta_shift(const float* __restrict__ raw, float* __restrict__ out) {
    int i = blockIdx.x * blockDim.x + threadIdx.x;
    if (i < NP * TD) out[i] = 0.5f * raw[i];
}

// ---------------------------------------------------------------------------
// k_cpab: unchanged (passing)
// ---------------------------------------------------------------------------
__global__ __launch_bounds__(256) void k_cpab(
    const float* __restrict__ x, const float* __restrict__ theta,
    const float* __restrict__ Bf, float scale, float* __restrict__ out)
{
    int gid = blockIdx.x * blockDim.x + threadIdx.x;
    if (gid >= NP * TT) return;
    int n = gid / TT, tt = gid % TT;

    float th[TD];
#pragma unroll
    for (int j = 0; j < TD; j++) th[j] = scale * theta[n * TD + j];

    float a[NCC], b[NCC];
#pragma unroll
    for (int i = 0; i < NCC; i++) {
        float aa = 0.f, bb = 0.f;
#pragma unroll
        for (int j = 0; j < TD; j++) {
            aa += th[j] * Bf[(2 * i) * TD + j];
            bb += th[j] * Bf[(2 * i + 1) * TD + j];
        }
        a[i] = aa; b[i] = bb;
    }

    float xc = (float)tt / 51.0f;
    for (int s = 0; s < 100; ++s) {
        float t6 = xc * 6.0f;
        float av = t6 < 1.f ? a[0] : t6 < 2.f ? a[1] : t6 < 3.f ? a[2]
                 : t6 < 4.f ? a[3] : t6 < 5.f ? a[4] : a[5];
        float bv = t6 < 1.f ? b[0] : t6 < 2.f ? b[1] : t6 < 3.f ? b[2]
                 : t6 < 4.f ? b[3] : t6 < 5.f ? b[4] : b[5];
        xc = xc + 0.01f * (av * xc + bv);
        xc = fminf(fmaxf(xc, 0.0f), 1.0f);
    }

    float pos = xc * 51.0f;
    int x0 = (int)floorf(pos);
    if (x0 < 0) x0 = 0;
    if (x0 > 50) x0 = 50;
    float w = pos - (float)x0;
    int bb_ = n >> 12, p = n & 4095;
    int base0 = ((x0 * BBAT + bb_) * CCH) * HWP + p;
#pragma unroll
    for (int ch = 0; ch < CCH; ++ch) {
        float d0 = x[base0 + ch * HWP];
        float d1 = x[base0 + ch * HWP + TSTRIDE];
        out[n * (CCH * TT) + ch * TT + tt] = d0 * (1.0f - w) + d1 * w;
    }
}

// ---------------------------------------------------------------------------
// k_loc (full-MFMA): wave = pixel; conv1, conv2 AND fc1 on matrix cores.
// Per tile (8 bt-pure tiles of 16 positions):
//   conv1/conv2 as round 7 (W frags preloaded from wimg)
//   LN64 via xor16/xor32; z2 (bf16) -> zP[pixel][k=pos*64+g] swizzled
//   barrier; fc1: D[j][pixel] += sum over 8 chunks/wave of
//     mfma(A = aimg chunk (direct global 16B loads), B = zP fragment)
// Epilogue: cross-wave D reduce in LDS, fc2 + tanh on wave 0.
// zP swizzle: byte = n*2048 + (k2 ^ (((k2>>7)&7)<<4) ^ nsw(n)),
//   nsw(n) = ((n&1)<<6)|((n>>1)<<4)  -> ~2-way conflicts both sides.
// ---------------------------------------------------------------------------
__global__ __launch_bounds__(256, 4) void k_loc(
    const float* __restrict__ x,     // [52,4,9,64,64]
    const float* __restrict__ xs,    // x_shift_pix [N,9,52]
    const int4v* __restrict__ wimg,  // conv fragment image
    const int4v* __restrict__ aimg,  // fc1w A-fragment image
    const float* __restrict__ b2c,
    const float* __restrict__ lncw,  const float* __restrict__ lncb,
    const float* __restrict__ fc1b,
    const float* __restrict__ fc2w,  const float* __restrict__ fc2b,
    float* __restrict__ outtheta)    // [N,5]
{
    __shared__ unsigned short zcl[4][128][8];  // c0..7 per pos (bf16)
    __shared__ unsigned int   zch[4][128];     // pk2(c8, bias) per pos
    __shared__ unsigned short y1b[4][16][64];  // [pos][f^sw] bf16
    __shared__ unsigned short zP[4][1024];     // z2 bf16 [pixel][k], swizzled
    __shared__ float dred[4][4][16];           // [wave][pixel][j]

    int tid  = threadIdx.x;
    int lane = tid & 63;
    int wv   = tid >> 6;
    int n    = blockIdx.x * 4 + wv;
    int bb_  = n >> 12, p = n & 4095;
    int pl   = lane & 15;
    int h    = lane >> 4;

    // ---- load pre-built fragments (coalesced b128) ----
    short8v w1a[4], w2a[4][2];
#pragma unroll
    for (int mt = 0; mt < 4; ++mt)
        w1a[mt] = __builtin_bit_cast(short8v, wimg[mt * 64 + lane]);
#pragma unroll
    for (int mt2 = 0; mt2 < 4; ++mt2)
#pragma unroll
        for (int ks = 0; ks < 2; ++ks)
            w2a[mt2][ks] = __builtin_bit_cast(short8v, wimg[(4 + mt2 * 2 + ks) * 64 + lane]);

    f32x4 b2v[4], lw4[4], lb4[4];
#pragma unroll
    for (int mt2 = 0; mt2 < 4; ++mt2) {
        b2v[mt2] = *(const f32x4*)(b2c  + mt2 * 16 + h * 4);
        lw4[mt2] = *(const f32x4*)(lncw + mt2 * 16 + h * 4);
        lb4[mt2] = *(const f32x4*)(lncb + mt2 * 16 + h * 4);
    }

    f32x4 dacc = (f32x4){0.f, 0.f, 0.f, 0.f};

    // ---- Phase A: LN9 per position (pos = bt*64 + tt; tt<52 valid) ----
#pragma unroll
    for (int r = 0; r < 2; ++r) {
        int pos = r * 64 + lane;
        int bt  = pos >> 6;
        int tt  = pos & 63;
        float zc[9], bias;
        if (tt < 52) {
            float xin[9];
            if (!bt) {
                int base = ((tt * BBAT + bb_) * CCH) * HWP + p;
#pragma unroll
                for (int c = 0; c < 9; ++c) xin[c] = x[base + c * HWP];
            } else {
                int base = n * (CCH * TT) + tt;
#pragma unroll
                for (int c = 0; c < 9; ++c) xin[c] = xs[base + c * TT];
            }
            float s1 = 0.f, s2 = 0.f;
#pragma unroll
            for (int c = 0; c < 9; ++c) { s1 += xin[c]; s2 += xin[c] * xin[c]; }
            float m  = s1 * (1.0f / 9.0f);
            float vv = fmaxf(s2 * (1.0f / 9.0f) - m * m, 0.f);
            float rs = rsqrtf(vv + 1e-5f);
#pragma unroll
            for (int c = 0; c < 9; ++c) zc[c] = (xin[c] - m) * rs;
            bias = 1.0f;
        } else {
#pragma unroll
            for (int c = 0; c < 9; ++c) zc[c] = 0.f;
            bias = 0.f;
        }
        *(int4v*)&zcl[wv][pos][0] =
            (int4v){(int)pk2(zc[0], zc[1]), (int)pk2(zc[2], zc[3]),
                    (int)pk2(zc[4], zc[5]), (int)pk2(zc[6], zc[7])};
        zch[wv][pos] = pk2(zc[8], bias);
    }

    int nsw_own = ((wv & 1) << 6) | ((wv >> 1) << 4);
    int ncl     = pl < 3 ? pl : 3;
    int nsw_rd  = ((ncl & 1) << 6) | ((ncl >> 1) << 4);

    // ---- tile loop ----
    for (int t = 0; t < 8; ++t) {
        int pos_g = t * 16 + pl;
        int sw    = (pl & 7) << 3;

        // conv1 B-fragment
        short8v b1f;
        if (h == 1) {
            unsigned zv = zch[wv][pos_g];
            b1f = __builtin_bit_cast(short8v, (int4v){(int)zv, 0, 0, 0});
        } else {
            b1f = *(const short8v*)&zcl[wv][pos_g][0];
        }

        // conv1 + relu -> y1buf (swizzled)
#pragma unroll
        for (int mt = 0; mt < 4; ++mt) {
            f32x4 c1 = __builtin_amdgcn_mfma_f32_16x16x32_bf16(
                w1a[mt], b1f, (f32x4){0.f, 0.f, 0.f, 0.f}, 0, 0, 0);
            float v0 = fmaxf(c1[0], 0.f), v1 = fmaxf(c1[1], 0.f);
            float v2 = fmaxf(c1[2], 0.f), v3 = fmaxf(c1[3], 0.f);
            int f0 = (mt * 16 + h * 4) ^ sw;
            *(int2v*)&y1b[wv][pl][f0] = (int2v){(int)pk2(v0, v1), (int)pk2(v2, v3)};
        }

        // conv2
        short8v b2f0 = *(const short8v*)&y1b[wv][pl][(h * 8) ^ sw];
        short8v b2f1 = *(const short8v*)&y1b[wv][pl][(32 + h * 8) ^ sw];
        float y2[4][4];
#pragma unroll
        for (int mt2 = 0; mt2 < 4; ++mt2) {
            f32x4 c2 = b2v[mt2];
            c2 = __builtin_amdgcn_mfma_f32_16x16x32_bf16(w2a[mt2][0], b2f0, c2, 0, 0, 0);
            c2 = __builtin_amdgcn_mfma_f32_16x16x32_bf16(w2a[mt2][1], b2f1, c2, 0, 0, 0);
            y2[mt2][0] = fmaxf(c2[0], 0.f);
            y2[mt2][1] = fmaxf(c2[1], 0.f);
            y2[mt2][2] = fmaxf(c2[2], 0.f);
            y2[mt2][3] = fmaxf(c2[3], 0.f);
        }

        // LN64
        float s = 0.f, q = 0.f;
#pragma unroll
        for (int mt2 = 0; mt2 < 4; ++mt2)
#pragma unroll
            for (int r = 0; r < 4; ++r) { s += y2[mt2][r]; q = fmaf(y2[mt2][r], y2[mt2][r], q); }
        s += __shfl_xor(s, 16, 64); s += __shfl_xor(s, 32, 64);
        q += __shfl_xor(q, 16, 64); q += __shfl_xor(q, 32, 64);
        float m2  = s * (1.0f / 64.0f);
        float v2_ = fmaxf(q * (1.0f / 64.0f) - m2 * m2, 0.f);
        float rs2 = rsqrtf(v2_ + 1e-5f);

        bool valid = (pos_g & 63) < 52;
#pragma unroll
        for (int mt2 = 0; mt2 < 4; ++mt2)
#pragma unroll
            for (int r = 0; r < 4; ++r) {
                float z = fmaf((y2[mt2][r] - m2) * rs2, lw4[mt2][r], lb4[mt2][r]);
                y2[mt2][r] = valid ? z : 0.f;
            }

        // write z2 pairs to zP (swizzled; k = pl*64 + g)
#pragma unroll
        for (int mt2 = 0; mt2 < 4; ++mt2)
#pragma unroll
            for (int rp = 0; rp < 2; ++rp) {
                int g0 = mt2 * 16 + h * 4 + rp * 2;
                int k2 = pl * 128 + g0 * 2;
                int byte = (wv << 11) + ((k2 ^ (((k2 >> 7) & 7) << 4)) ^ nsw_own);
                *(unsigned*)((char*)zP + byte) = pk2(y2[mt2][rp * 2], y2[mt2][rp * 2 + 1]);
            }
        __syncthreads();

        // fc1 MFMA: wave handles chunks wv*8 .. wv*8+7 of this tile's K=1024
        const int4v* abase = aimg + (t * 32 + wv * 8) * 64 + lane;
#pragma unroll
        for (int cc = 0; cc < 8; ++cc) {
            int c = wv * 8 + cc;
            short8v afrag = __builtin_bit_cast(short8v, abase[cc * 64]);
            int k2 = c * 64 + h * 16;
            int byte = (ncl << 11) + ((k2 ^ (((k2 >> 7) & 7) << 4)) ^ nsw_rd);
            short8v bfrag = *(const short8v*)((const char*)zP + byte);
            dacc = __builtin_amdgcn_mfma_f32_16x16x32_bf16(afrag, bfrag, dacc, 0, 0, 0);
        }
        __syncthreads();
    }

    // ---- epilogue: cross-wave reduce + fc2 + tanh ----
    if (pl < 4) *(f32x4*)&dred[wv][pl][h * 4] = dacc;
    __syncthreads();
    if (wv == 0) {
        int n4 = lane >> 4, j = lane & 15;
        float hj = dred[0][n4][j] + dred[1][n4][j] + dred[2][n4][j] + dred[3][n4][j];
        hj = fmaxf(hj + fc1b[j], 0.f);
        float th[5];
#pragma unroll
        for (int d = 0; d < 5; ++d) {
            float sd = hj * fc2w[j * 5 + d];
            sd += __shfl_xor(sd, 1, 64); sd += __shfl_xor(sd, 2, 64);
            sd += __shfl_xor(sd, 4, 64); sd += __shfl_xor(sd, 8, 64);
            th[d] = sd;
        }
        if (j < 5) outtheta[(blockIdx.x * 4 + n4) * TD + j] = tanhf(th[j] + fc2b[j]);
    }
}

// ---------------------------------------------------------------------------
extern "C" void kernel_launch(void* const* d_in, const int* in_sizes, int n_in,
                              void* d_out, int out_size, void* d_ws, size_t ws_size,
                              hipStream_t stream) {
    const float* x     = (const float*)d_in[0];
    const float* thraw = (const float*)d_in[1];
    const float* lniw  = (const float*)d_in[2];
    const float* lnib  = (const float*)d_in[3];
    const float* w1c   = (const float*)d_in[4];
    const float* b1c   = (const float*)d_in[5];
    const float* w2c   = (const float*)d_in[6];
    const float* b2c   = (const float*)d_in[7];
    const float* lncw  = (const float*)d_in[8];
    const float* lncb  = (const float*)d_in[9];
    const float* fc1w  = (const float*)d_in[10];
    const float* fc1b  = (const float*)d_in[11];
    const float* fc2w  = (const float*)d_in[12];
    const float* fc2b  = (const float*)d_in[13];
    float* out  = (float*)d_out;
    float* ws   = (float*)d_ws;
    float* Bf   = ws + WS_BF;
    int4v* wimg = (int4v*)(ws + WS_WIMG);
    int4v* aimg = (int4v*)(ws + WS_AIMG);

    hipLaunchKernelGGL(k_basis, dim3(1), dim3(64), 0, stream, Bf);
    hipLaunchKernelGGL(k_prepw, dim3(1), dim3(64), 0, stream, lniw, lnib, w1c, b1c, w2c, wimg);
    hipLaunchKernelGGL(k_prepa, dim3(64), dim3(256), 0, stream, fc1w, aimg);
    hipLaunchKernelGGL(k_theta_shift, dim3((NP * TD + 255) / 256), dim3(256), 0, stream,
                       thraw, out + OUT3);
    hipLaunchKernelGGL(k_cpab, dim3((NP * TT) / 256), dim3(256), 0, stream,
                       x, thraw, Bf, 0.5f, out + OUT1);
    hipLaunchKernelGGL(k_loc, dim3(NP / 4), dim3(256), 0, stream,
                       x, out + OUT1, wimg, aimg, b2c, lncw, lncb,
                       fc1b, fc2w, fc2b, out + OUT2);
    hipLaunchKernelGGL(k_cpab, dim3((NP * TT) / 256), dim3(256), 0, stream,
                       x, out + OUT2, Bf, 1.0f, out + OUT0);
}

// Round 9
// 304.233 us; speedup vs baseline: 4.4233x; 1.4634x over previous
//
#include <hip/hip_runtime.h>
#include <math.h>

// Problem constants
#define TT   52        // time steps
#define BBAT 4         // batch
#define CCH  9         // input channels
#define HWP  4096      // 64*64 pixels per image
#define FF   64        // features
#define NP   16384     // b*h*w pixels
#define TD   5         // theta dim
#define NCC  6         // tessellation cells
#define TSTRIDE 147456 // b*c*h*w (stride of t in x, floats)

// output offsets (floats)
#define OUT0 0
#define OUT1 (NP*CCH*TT)        // x_shift_pix
#define OUT2 (2*NP*CCH*TT)      // theta_pred
#define OUT3 (OUT2 + NP*TD)     // theta_shift

// workspace offsets (floats)
#define WS_BF    0      // 60 floats: CPAB basis
#define WS_WIMG  1024   // 12*64 int4: w1a/w2a fragment image
#define WS_AIMG  4096   // 8*32*64 int4 = 65536 floats: fc1w A-fragment image
#define WS_XPIX  69632  // NP*CCH*TT floats: x in pixel-major [n][c][t] (optional)

typedef __attribute__((ext_vector_type(8)))  short short8v;
typedef __attribute__((ext_vector_type(4)))  float f32x4;
typedef __attribute__((ext_vector_type(4)))  int   int4v;
typedef __attribute__((ext_vector_type(2)))  int   int2v;

// RNE f32->bf16 bits, packed pair
__device__ __forceinline__ unsigned bfb(float f) {
    unsigned x = __builtin_bit_cast(unsigned, f);
    return (x + 0x7fffu + ((x >> 16) & 1u)) >> 16;
}
__device__ __forceinline__ unsigned pk2(float a, float b) {
    return bfb(a) | (bfb(b) << 16);
}
// zP row-XOR helper: uniform over 16 rows (XOR-fold, each 3-bit value twice)
__device__ __forceinline__ int nswz(int n) {
    return (((n ^ (n >> 3)) & 1) << 6) | (((n >> 1) & 3) << 4);
}

// ---------------------------------------------------------------------------
// k_basis: reproduce np.linalg.svd(L) null-space basis (Vt[7:].T) exactly.
// ---------------------------------------------------------------------------
__global__ void k_basis(float* __restrict__ Bout) {
    int k = threadIdx.x;
    double Acol[7], Vcol[7], Mcol[5];
#pragma unroll
    for (int r = 0; r < 7; r++) { Acol[r] = 0.0; Vcol[r] = 0.0; }
#pragma unroll
    for (int j = 0; j < 5; j++) Mcol[j] = 0.0;

    if (k < 12) {
#pragma unroll
        for (int j = 1; j < 6; j++) {
            int r = j - 1;
            double xj = (double)j / 6.0;
            if (k == 2 * (j - 1))     Acol[r] = xj;
            if (k == 2 * (j - 1) + 1) Acol[r] = 1.0;
            if (k == 2 * j)           Acol[r] = -xj;
            if (k == 2 * j + 1)       Acol[r] = -1.0;
        }
        if (k == 1)  Acol[5] = 1.0;
        if (k == 10) Acol[6] = 1.0;
        if (k == 11) Acol[6] = 1.0;
#pragma unroll
        for (int j = 0; j < 5; j++) Mcol[j] = (k == 7 + j) ? 1.0 : 0.0;
    }

    double tau[7];
#pragma unroll
    for (int i = 0; i < 7; i++) {
        double c = (k > i && k < 12) ? Acol[i] * Acol[i] : 0.0;
#pragma unroll
        for (int off = 1; off < 64; off <<= 1) c += __shfl_xor(c, off, 64);
        double alpha = __shfl(Acol[i], i, 64);
        double t_i, vk;
        if (c == 0.0) {
            t_i = 0.0;
            vk = (k == i) ? 1.0 : 0.0;
        } else {
            double nrm  = sqrt(alpha * alpha + c);
            double beta = (alpha >= 0.0) ? -nrm : nrm;  // Fortran SIGN
            t_i = (beta - alpha) / beta;
            double inv = 1.0 / (alpha - beta);
            vk = (k == i) ? 1.0 : ((k > i && k < 12) ? Acol[i] * inv : 0.0);
        }
        tau[i]  = t_i;
        Vcol[i] = vk;
#pragma unroll
        for (int r = 0; r < 7; r++) {
            if (r > i) {
                double w = Acol[r] * vk;
#pragma unroll
                for (int off = 1; off < 64; off <<= 1) w += __shfl_xor(w, off, 64);
                Acol[r] -= t_i * w * vk;
            }
        }
    }
#pragma unroll
    for (int i = 6; i >= 0; i--) {
#pragma unroll
        for (int j = 0; j < 5; j++) {
            double w = Mcol[j] * Vcol[i];
#pragma unroll
            for (int off = 1; off < 64; off <<= 1) w += __shfl_xor(w, off, 64);
            Mcol[j] -= tau[i] * w * Vcol[i];
        }
    }
    if (k < 12) {
#pragma unroll
        for (int j = 0; j < 5; j++) Bout[k * 5 + j] = (float)Mcol[j];
    }
}

// ---------------------------------------------------------------------------
// k_prepw: conv1/conv2 MFMA A-fragments -> wimg[12][64] int4.
// ---------------------------------------------------------------------------
__global__ void k_prepw(const float* __restrict__ lniw, const float* __restrict__ lnib,
                        const float* __restrict__ w1c,  const float* __restrict__ b1c,
                        const float* __restrict__ w2c,  int4v* __restrict__ wimg) {
    int lane = threadIdx.x;
    int pl = lane & 15, h = lane >> 4;
#pragma unroll
    for (int mt = 0; mt < 4; ++mt) {
        int f = mt * 16 + pl;
        float b0f = b1c[f];
#pragma unroll
        for (int c = 0; c < 9; ++c) b0f += lnib[c] * w1c[c * 64 + f];
        float v[8];
#pragma unroll
        for (int i = 0; i < 8; ++i) {
            int c  = h * 8 + i;
            int cc = c < 9 ? c : 8;
            float lv = lniw[cc] * w1c[cc * 64 + f];
            v[i] = (c < 9) ? lv : ((c == 9) ? b0f : 0.f);
        }
        wimg[mt * 64 + lane] = (int4v){(int)pk2(v[0],v[1]), (int)pk2(v[2],v[3]),
                                       (int)pk2(v[4],v[5]), (int)pk2(v[6],v[7])};
    }
#pragma unroll
    for (int mt2 = 0; mt2 < 4; ++mt2) {
        int g = mt2 * 16 + pl;
#pragma unroll
        for (int ks = 0; ks < 2; ++ks) {
            float v[8];
#pragma unroll
            for (int i = 0; i < 8; ++i) v[i] = w2c[(ks * 32 + h * 8 + i) * 64 + g];
            wimg[(4 + mt2 * 2 + ks) * 64 + lane] =
                (int4v){(int)pk2(v[0],v[1]), (int)pk2(v[2],v[3]),
                        (int)pk2(v[4],v[5]), (int)pk2(v[6],v[7])};
        }
    }
}

// ---------------------------------------------------------------------------
// k_prepa: fc1w -> bf16 A-fragment image (k = pos_l*64 + g within tile).
// ---------------------------------------------------------------------------
__global__ void k_prepa(const float* __restrict__ fc1w, int4v* __restrict__ aimg) {
    int gid  = blockIdx.x * 256 + threadIdx.x;   // 16384 total
    int lane = gid & 63;
    int tc   = gid >> 6;
    int t = tc >> 5, c = tc & 31;
    int bt = t >> 2, tt0 = (t & 3) << 4;
    int m = lane & 15, h = lane >> 4;
    float v[8];
#pragma unroll
    for (int i = 0; i < 8; ++i) {
        int k = c * 32 + h * 8 + i;
        int pos_l = k >> 6, g = k & 63;
        int tt = tt0 + pos_l;
        v[i] = (tt < 52) ? fc1w[(bt * 3328 + g * 52 + tt) * 16 + m] : 0.f;
    }
    aimg[gid] = (int4v){(int)pk2(v[0],v[1]), (int)pk2(v[2],v[3]),
                        (int)pk2(v[4],v[5]), (int)pk2(v[6],v[7])};
}

// ---------------------------------------------------------------------------
// k_t2p: x [t,b,c,h,w] -> xp [n][c][t] (pixel-major), LDS-tiled transpose.
// grid = 4b * 9c * 64 ptiles.
// ---------------------------------------------------------------------------
__global__ __launch_bounds__(256) void k_t2p(const float* __restrict__ x,
                                             float* __restrict__ xp) {
    __shared__ float ld[52 * 65];
    int blk = blockIdx.x;
    int b = blk / 576, rem = blk % 576, c = rem >> 6, pt = rem & 63;
    int p0 = pt * 64;
    for (int idx = threadIdx.x; idx < 52 * 64; idx += 256) {
        int t = idx >> 6, pp = idx & 63;
        ld[t * 65 + pp] = x[((t * BBAT + b) * CCH + c) * HWP + p0 + pp];
    }
    __syncthreads();
    int pn = threadIdx.x >> 2, tq = threadIdx.x & 3;
    float* dst = xp + (size_t)(b * HWP + p0 + pn) * (CCH * TT) + c * TT + tq * 13;
#pragma unroll
    for (int k = 0; k < 13; ++k) dst[k] = ld[(tq * 13 + k) * 65 + pn];
}

// ---------------------------------------------------------------------------
__global__ void k_theta_shift(const float* __restrict__ raw, float* __restrict__ out) {
    int i = blockIdx.x * blockDim.x + threadIdx.x;
    if (i < NP * TD) out[i] = 0.5f * raw[i];
}

// ---------------------------------------------------------------------------
// k_cpab: ODE + lerp; gathers from pixel-major xp when available.
// ---------------------------------------------------------------------------
__global__ __launch_bounds__(256) void k_cpab(
    const float* __restrict__ x, const float* __restrict__ xp, int use_xp,
    const float* __restrict__ theta, const float* __restrict__ Bf,
    float scale, float* __restrict__ out)
{
    int gid = blockIdx.x * blockDim.x + threadIdx.x;
    if (gid >= NP * TT) return;
    int n = gid / TT, tt = gid % TT;

    float th[TD];
#pragma unroll
    for (int j = 0; j < TD; j++) th[j] = scale * theta[n * TD + j];

    float a[NCC], b[NCC];
#pragma unroll
    for (int i = 0; i < NCC; i++) {
        float aa = 0.f, bb = 0.f;
#pragma unroll
        for (int j = 0; j < TD; j++) {
            aa += th[j] * Bf[(2 * i) * TD + j];
            bb += th[j] * Bf[(2 * i + 1) * TD + j];
        }
        a[i] = aa; b[i] = bb;
    }

    float xc = (float)tt / 51.0f;
    for (int s = 0; s < 100; ++s) {
        float t6 = xc * 6.0f;
        float av = t6 < 1.f ? a[0] : t6 < 2.f ? a[1] : t6 < 3.f ? a[2]
                 : t6 < 4.f ? a[3] : t6 < 5.f ? a[4] : a[5];
        float bv = t6 < 1.f ? b[0] : t6 < 2.f ? b[1] : t6 < 3.f ? b[2]
                 : t6 < 4.f ? b[3] : t6 < 5.f ? b[4] : b[5];
        xc = xc + 0.01f * (av * xc + bv);
        xc = fminf(fmaxf(xc, 0.0f), 1.0f);
    }

    float pos = xc * 51.0f;
    int x0 = (int)floorf(pos);
    if (x0 < 0) x0 = 0;
    if (x0 > 50) x0 = 50;
    float w = pos - (float)x0;
    if (use_xp) {
        const float* row = xp + (size_t)n * (CCH * TT);
#pragma unroll
        for (int ch = 0; ch < CCH; ++ch) {
            float d0 = row[ch * TT + x0];
            float d1 = row[ch * TT + x0 + 1];
            out[n * (CCH * TT) + ch * TT + tt] = d0 * (1.0f - w) + d1 * w;
        }
    } else {
        int bb_ = n >> 12, p = n & 4095;
        int base0 = ((x0 * BBAT + bb_) * CCH) * HWP + p;
#pragma unroll
        for (int ch = 0; ch < CCH; ++ch) {
            float d0 = x[base0 + ch * HWP];
            float d1 = x[base0 + ch * HWP + TSTRIDE];
            out[n * (CCH * TT) + ch * TT + tt] = d0 * (1.0f - w) + d1 * w;
        }
    }
}

// ---------------------------------------------------------------------------
// k_loc (full-MFMA, 16 pixels/block): 4 waves, pixels = blockIdx*16 + 0..15.
// Per tile (8 bt-pure tiles of 16 positions):
//   LN9 stage: thread = (px, pos); coalesced x/xs reads (16 px = one 64B line)
//   conv: each wave runs 4 pixels (wv*4+sub): conv1/conv2 MFMA, LN64, z2->zP
//   fc1: D[j16][px16] += mfma(aimg chunk, zP fragment) — all 16 cols real
// Epilogue: cross-wave reduce (LDS) + fc2 + tanh, all 16 pixels.
// ---------------------------------------------------------------------------
__global__ __launch_bounds__(256, 3) void k_loc(
    const float* __restrict__ x,     // [52,4,9,64,64]
    const float* __restrict__ xs,    // x_shift_pix [N,9,52]
    const int4v* __restrict__ wimg,  // conv fragment image
    const int4v* __restrict__ aimg,  // fc1w A-fragment image
    const float* __restrict__ b2c,
    const float* __restrict__ lncw,  const float* __restrict__ lncb,
    const float* __restrict__ fc1b,
    const float* __restrict__ fc2w,  const float* __restrict__ fc2b,
    float* __restrict__ outtheta)    // [N,5]
{
    __shared__ int4v          zcs[256];        // 4KB  zc lo-8 per (px,pos), swizzled
    __shared__ unsigned       zchs[256];       // 1KB  pk2(c8, bias)
    __shared__ unsigned short y1b[4][16][64];  // 8KB  per-wave y1 tile
    __shared__ unsigned short zP[16][1024];    // 32KB z2 [px][k], swizzled
    __shared__ float          dred[4][16][16]; // 4KB  [wave][px][j]

    int tid    = threadIdx.x;
    int lane   = tid & 63;
    int wv     = tid >> 6;
    int base16 = blockIdx.x * 16;
    int bb_    = base16 >> 12, p0 = base16 & 4095;
    int pl     = lane & 15;
    int h      = lane >> 4;

    // ---- fragments (coalesced b128 from wimg) ----
    short8v w1a[4], w2a[4][2];
#pragma unroll
    for (int mt = 0; mt < 4; ++mt)
        w1a[mt] = __builtin_bit_cast(short8v, wimg[mt * 64 + lane]);
#pragma unroll
    for (int mt2 = 0; mt2 < 4; ++mt2)
#pragma unroll
        for (int ks = 0; ks < 2; ++ks)
            w2a[mt2][ks] = __builtin_bit_cast(short8v, wimg[(4 + mt2 * 2 + ks) * 64 + lane]);

    f32x4 b2v[4], lw4[4], lb4[4];
#pragma unroll
    for (int mt2 = 0; mt2 < 4; ++mt2) {
        b2v[mt2] = *(const f32x4*)(b2c  + mt2 * 16 + h * 4);
        lw4[mt2] = *(const f32x4*)(lncw + mt2 * 16 + h * 4);
        lb4[mt2] = *(const f32x4*)(lncb + mt2 * 16 + h * 4);
    }

    f32x4 dacc = (f32x4){0.f, 0.f, 0.f, 0.f};

    for (int t = 0; t < 8; ++t) {
        int bt = t >> 2, tt0 = (t & 3) << 4;

        // ---- LN9 stage: one (px, pos) per thread, coalesced ----
        {
            int px, q;
            if (bt == 0) { px = tid & 15; q = tid >> 4; }   // lanes = px (line-coalesced)
            else         { px = tid >> 4; q = tid & 15; }   // lanes = tt (row-coalesced)
            int tt = tt0 + q;
            float zc[9], bias;
            if (tt < 52) {
                float xin[9];
                if (bt == 0) {
                    int base = ((tt * BBAT + bb_) * CCH) * HWP + p0 + px;
#pragma unroll
                    for (int c = 0; c < 9; ++c) xin[c] = x[base + c * HWP];
                } else {
                    int base = (base16 + px) * (CCH * TT) + tt;
#pragma unroll
                    for (int c = 0; c < 9; ++c) xin[c] = xs[base + c * TT];
                }
                float s1 = 0.f, s2 = 0.f;
#pragma unroll
                for (int c = 0; c < 9; ++c) { s1 += xin[c]; s2 += xin[c] * xin[c]; }
                float m  = s1 * (1.0f / 9.0f);
                float vv = fmaxf(s2 * (1.0f / 9.0f) - m * m, 0.f);
                float rs = rsqrtf(vv + 1e-5f);
#pragma unroll
                for (int c = 0; c < 9; ++c) zc[c] = (xin[c] - m) * rs;
                bias = 1.0f;
            } else {
#pragma unroll
                for (int c = 0; c < 9; ++c) zc[c] = 0.f;
                bias = 0.f;
            }
            zcs[px * 16 + (q ^ (px & 7))] =
                (int4v){(int)pk2(zc[0], zc[1]), (int)pk2(zc[2], zc[3]),
                        (int)pk2(zc[4], zc[5]), (int)pk2(zc[6], zc[7])};
            zchs[px * 16 + q] = pk2(zc[8], bias);
        }
        __syncthreads();

        // ---- conv: 4 pixels per wave ----
        int sw = (pl & 7) << 3;
#pragma unroll
        for (int sub = 0; sub < 4; ++sub) {
            int px = wv * 4 + sub;
            int nswp = nswz(px);

            short8v b1f;
            if (h == 1) {
                unsigned zv = zchs[px * 16 + pl];
                b1f = __builtin_bit_cast(short8v, (int4v){(int)zv, 0, 0, 0});
            } else {
                b1f = __builtin_bit_cast(short8v, zcs[px * 16 + (pl ^ (px & 7))]);
            }

#pragma unroll
            for (int mt = 0; mt < 4; ++mt) {
                f32x4 c1 = __builtin_amdgcn_mfma_f32_16x16x32_bf16(
                    w1a[mt], b1f, (f32x4){0.f, 0.f, 0.f, 0.f}, 0, 0, 0);
                float v0 = fmaxf(c1[0], 0.f), v1 = fmaxf(c1[1], 0.f);
                float v2 = fmaxf(c1[2], 0.f), v3 = fmaxf(c1[3], 0.f);
                int f0 = (mt * 16 + h * 4) ^ sw;
                *(int2v*)&y1b[wv][pl][f0] = (int2v){(int)pk2(v0, v1), (int)pk2(v2, v3)};
            }

            short8v b2f0 = *(const short8v*)&y1b[wv][pl][(h * 8) ^ sw];
            short8v b2f1 = *(const short8v*)&y1b[wv][pl][(32 + h * 8) ^ sw];
            float y2[4][4];
#pragma unroll
            for (int mt2 = 0; mt2 < 4; ++mt2) {
                f32x4 c2 = b2v[mt2];
                c2 = __builtin_amdgcn_mfma_f32_16x16x32_bf16(w2a[mt2][0], b2f0, c2, 0, 0, 0);
                c2 = __builtin_amdgcn_mfma_f32_16x16x32_bf16(w2a[mt2][1], b2f1, c2, 0, 0, 0);
                y2[mt2][0] = fmaxf(c2[0], 0.f);
                y2[mt2][1] = fmaxf(c2[1], 0.f);
                y2[mt2][2] = fmaxf(c2[2], 0.f);
                y2[mt2][3] = fmaxf(c2[3], 0.f);
            }

            // LN64
            float s = 0.f, q = 0.f;
#pragma unroll
            for (int mt2 = 0; mt2 < 4; ++mt2)
#pragma unroll
                for (int r = 0; r < 4; ++r) { s += y2[mt2][r]; q = fmaf(y2[mt2][r], y2[mt2][r], q); }
            s += __shfl_xor(s, 16, 64); s += __shfl_xor(s, 32, 64);
            q += __shfl_xor(q, 16, 64); q += __shfl_xor(q, 32, 64);
            float m2  = s * (1.0f / 64.0f);
            float v2_ = fmaxf(q * (1.0f / 64.0f) - m2 * m2, 0.f);
            float rs2 = rsqrtf(v2_ + 1e-5f);

            bool valid = (tt0 + pl) < 52;
#pragma unroll
            for (int mt2 = 0; mt2 < 4; ++mt2)
#pragma unroll
                for (int r = 0; r < 4; ++r) {
                    float z = fmaf((y2[mt2][r] - m2) * rs2, lw4[mt2][r], lb4[mt2][r]);
                    y2[mt2][r] = valid ? z : 0.f;
                }

            // z2 pairs -> zP (swizzled)
#pragma unroll
            for (int mt2 = 0; mt2 < 4; ++mt2)
#pragma unroll
                for (int rp = 0; rp < 2; ++rp) {
                    int g0 = mt2 * 16 + h * 4 + rp * 2;
                    int k2 = pl * 128 + g0 * 2;
                    int byte = (px << 11) + ((k2 ^ (((k2 >> 7) & 7) << 4)) ^ nswp);
                    *(unsigned*)((char*)zP + byte) = pk2(y2[mt2][rp * 2], y2[mt2][rp * 2 + 1]);
                }
        }
        __syncthreads();

        // ---- fc1 MFMA: wave covers chunks wv*8..wv*8+7 (K=256 of 1024) ----
        const int4v* abase = aimg + (t * 32 + wv * 8) * 64 + lane;
        int nswr = nswz(pl);
#pragma unroll
        for (int cc = 0; cc < 8; ++cc) {
            int c = wv * 8 + cc;
            short8v afrag = __builtin_bit_cast(short8v, abase[cc * 64]);
            int k2 = c * 64 + h * 16;
            int byte = (pl << 11) + ((k2 ^ (((k2 >> 7) & 7) << 4)) ^ nswr);
            short8v bfrag = *(const short8v*)((const char*)zP + byte);
            dacc = __builtin_amdgcn_mfma_f32_16x16x32_bf16(afrag, bfrag, dacc, 0, 0, 0);
        }
        __syncthreads();
    }

    // ---- epilogue: cross-wave reduce + fc2 + tanh (16 pixels) ----
    *(f32x4*)&dred[wv][pl][h * 4] = dacc;
    __syncthreads();
    {
        int n4 = tid >> 4, j = tid & 15;
        float hj = dred[0][n4][j] + dred[1][n4][j] + dred[2][n4][j] + dred[3][n4][j];
        hj = fmaxf(hj + fc1b[j], 0.f);
        float th[5];
#pragma unroll
        for (int d = 0; d < 5; ++d) {
            float sd = hj * fc2w[j * 5 + d];
            sd += __shfl_xor(sd, 1, 64); sd += __shfl_xor(sd, 2, 64);
            sd += __shfl_xor(sd, 4, 64); sd += __shfl_xor(sd, 8, 64);
            th[d] = sd;
        }
        if (j < 5) outtheta[(base16 + n4) * TD + j] = tanhf(th[j] + fc2b[j]);
    }
}

// ---------------------------------------------------------------------------
extern "C" void kernel_launch(void* const* d_in, const int* in_sizes, int n_in,
                              void* d_out, int out_size, void* d_ws, size_t ws_size,
                              hipStream_t stream) {
    const float* x     = (const float*)d_in[0];
    const float* thraw = (const float*)d_in[1];
    const float* lniw  = (const float*)d_in[2];
    const float* lnib  = (const float*)d_in[3];
    const float* w1c   = (const float*)d_in[4];
    const float* b1c   = (const float*)d_in[5];
    const float* w2c   = (const float*)d_in[6];
    const float* b2c   = (const float*)d_in[7];
    const float* lncw  = (const float*)d_in[8];
    const float* lncb  = (const float*)d_in[9];
    const float* fc1w  = (const float*)d_in[10];
    const float* fc1b  = (const float*)d_in[11];
    const float* fc2w  = (const float*)d_in[12];
    const float* fc2b  = (const float*)d_in[13];
    float* out  = (float*)d_out;
    float* ws   = (float*)d_ws;
    float* Bf   = ws + WS_BF;
    int4v* wimg = (int4v*)(ws + WS_WIMG);
    int4v* aimg = (int4v*)(ws + WS_AIMG);
    float* xp   = ws + WS_XPIX;
    int use_xp  = (ws_size >= (size_t)(WS_XPIX + NP * CCH * TT) * 4) ? 1 : 0;

    hipLaunchKernelGGL(k_basis, dim3(1), dim3(64), 0, stream, Bf);
    hipLaunchKernelGGL(k_prepw, dim3(1), dim3(64), 0, stream, lniw, lnib, w1c, b1c, w2c, wimg);
    hipLaunchKernelGGL(k_prepa, dim3(64), dim3(256), 0, stream, fc1w, aimg);
    hipLaunchKernelGGL(k_theta_shift, dim3((NP * TD + 255) / 256), dim3(256), 0, stream,
                       thraw, out + OUT3);
    if (use_xp)
        hipLaunchKernelGGL(k_t2p, dim3(2304), dim3(256), 0, stream, x, xp);
    hipLaunchKernelGGL(k_cpab, dim3((NP * TT) / 256), dim3(256), 0, stream,
                       x, xp, use_xp, thraw, Bf, 0.5f, out + OUT1);
    hipLaunchKernelGGL(k_loc, dim3(NP / 16), dim3(256), 0, stream,
                       x, out + OUT1, wimg, aimg, b2c, lncw, lncb,
                       fc1b, fc2w, fc2b, out + OUT2);
    hipLaunchKernelGGL(k_cpab, dim3((NP * TT) / 256), dim3(256), 0, stream,
                       x, xp, use_xp, out + OUT2, Bf, 1.0f, out + OUT0);
}